// Round 1
// baseline (839.313 us; speedup 1.0000x reference)
//
#include <hip/hip_runtime.h>
#include <hip/hip_bf16.h>
#include <math.h>

#define DEV __device__ __forceinline__

static constexpr int HW  = 4096;   // H*W
static constexpr int POS = 8192;   // B*H*W

// ---------- B-spline basis (order 3), mirrors reference Cox-de Boor ----------
template<int G>
DEV void bsplines(float x, float* out /* G+3 values */) {
  const float h = 2.0f / (float)G;
  float knot[G + 7];
#pragma unroll
  for (int t = 0; t < G + 7; ++t) knot[t] = -1.0f + (float)(t - 3) * h;
  float bb[G + 6];
#pragma unroll
  for (int t = 0; t < G + 6; ++t) bb[t] = (x >= knot[t] && x < knot[t + 1]) ? 1.0f : 0.0f;
#pragma unroll
  for (int j = 1; j <= 3; ++j) {
#pragma unroll
    for (int t = 0; t < G + 6 - j; ++t) {
      float left  = (x - knot[t]) / (knot[t + j] - knot[t]);
      float right = (knot[t + j + 1] - x) / (knot[t + j + 1] - knot[t + 1]);
      bb[t] = left * bb[t] + right * bb[t + 1];
    }
  }
#pragma unroll
  for (int t = 0; t < G + 3; ++t) out[t] = bb[t];
}

DEV float sigmoidf_(float x) { return 1.0f / (1.0f + __expf(-x)); }

DEV float block_reduce_256(float v, float* sb) {  // blockDim.x == 256
  __syncthreads();
#pragma unroll
  for (int off = 32; off > 0; off >>= 1) v += __shfl_down(v, off, 64);
  int lane = threadIdx.x & 63, wid = threadIdx.x >> 6;
  if (lane == 0) sb[wid] = v;
  __syncthreads();
  return sb[0] + sb[1] + sb[2] + sb[3];
}

// ---------- features: F[b][h][ic][wp], ic = c*64+i, w padded by D with features(0) ----------
template<int G, int D>
__global__ void features_k(const float* __restrict__ x, __hip_bfloat16* __restrict__ F) {
  constexpr int CF = G + 4;
  constexpr int NB = G + 3;
  constexpr int WP = 64 + 2 * D;
  constexpr int KC = 64 * CF;
  int lin = blockIdx.x * 256 + threadIdx.x;            // [0, 524288)
  int w = lin & 63, h = (lin >> 6) & 63, i = (lin >> 12) & 63, b = lin >> 18;
  float xv = x[lin];                                   // x is (B,Ci,H,W): same flat index
  float s = xv * sigmoidf_(xv);                        // silu
  float bas[NB];
  bsplines<G>(xv, bas);
  size_t rowbase = (size_t)(b * 64 + h) * KC * WP;
  __hip_bfloat16* Fp = F + rowbase + (size_t)i * WP + (D + w);
  Fp[0] = __float2bfloat16(s);
#pragma unroll
  for (int c = 1; c < CF; ++c) Fp[(size_t)c * 64 * WP] = __float2bfloat16(bas[c - 1]);
  if (w < 2 * D) {
    int wp = (w < D) ? w : (64 + w);
    float b0[NB];
    bsplines<G>(0.0f, b0);
    __hip_bfloat16* Gp = F + rowbase + (size_t)i * WP + wp;
    Gp[0] = __float2bfloat16(0.0f);
#pragma unroll
    for (int c = 1; c < CF; ++c) Gp[(size_t)c * 64 * WP] = __float2bfloat16(b0[c - 1]);
  }
}

// ---------- weight repack: Wt[k][ic][o], ic = c*64+i ----------
__global__ void wprep_k(const float* __restrict__ base_w, const float* __restrict__ spline_w,
                        float* __restrict__ Wt, int NB, int KC) {
  int lin = blockIdx.x * 256 + threadIdx.x;  // = (k*KC + ic)*64 + o
  int o = lin & 63;
  int ic = (lin >> 6) % KC;
  int k  = (lin >> 6) / KC;
  int c = ic >> 6, i = ic & 63;
  float v = (c == 0) ? base_w[(o * 64 + i) * 9 + k]
                     : spline_w[((o * 64 + i) * 9 + k) * NB + (c - 1)];
  Wt[lin] = v;
}

// ---------- C0[k][o]: contribution of a fully h-OOB tap (features of zero input) ----------
template<int G>
__global__ void c0_k(const float* __restrict__ Wt, float* __restrict__ C0, int broff) {
  constexpr int NB = G + 3, CF = G + 4, KC = 64 * CF;
  int k = blockIdx.x, o = threadIdx.x;
  float b0[NB];
  bsplines<G>(0.0f, b0);
  float sum = 0.0f;
  for (int c = 1; c < CF; ++c) {
    float bv = b0[c - 1];
    const float* p = Wt + (size_t)(k * KC + c * 64) * 64 + o;
#pragma unroll 4
    for (int i = 0; i < 64; ++i) sum += p[i * 64] * bv;
  }
  C0[(broff + k) * 64 + o] = sum;
}

// ---------- x mean over (H,W) per (b,i) ----------
__global__ void xmean_k(const float* __restrict__ x, float* __restrict__ xm) {
  int bi = blockIdx.x;  // [0,128)
  const float* p = x + (size_t)bi * HW;
  float s = 0.0f;
  for (int t = threadIdx.x; t < HW; t += 256) s += p[t];
  __shared__ float sb[4];
  s = block_reduce_256(s, sb);
  if (threadIdx.x == 0) xm[bi] = s * (1.0f / HW);
}

// ---------- KAN conv: 9-tap implicit GEMM, y[br][b][h][o][w] ----------
__global__ __launch_bounds__(256) void conv_k(
    const __hip_bfloat16* __restrict__ F0, const __hip_bfloat16* __restrict__ F1,
    const __hip_bfloat16* __restrict__ F2,
    const float* __restrict__ Wt0, const float* __restrict__ Wt1, const float* __restrict__ Wt2,
    const float* __restrict__ C0, float* __restrict__ y) {
  int bid = blockIdx.x;                 // [0,384)
  int br = bid >> 7, r = bid & 127, b = r >> 6, h = r & 63;
  const __hip_bfloat16* F = (br == 0) ? F0 : ((br == 1) ? F1 : F2);
  const float* Wt = (br == 0) ? Wt0 : ((br == 1) ? Wt1 : Wt2);
  int dd = 6 * (br + 1);
  int G  = 3 * (br + 1);
  int CF = G + 4, KC = 64 * CF, WP = 64 + 2 * dd;

  int tid = threadIdx.x;
  int wg = tid & 15, og = tid >> 4;
  int w0 = wg * 4, o0 = og * 4;
  float acc[4][4] = {};

  __shared__ float As[64][64];
  __shared__ float Ws[64][64];

  for (int k = 0; k < 9; ++k) {
    int ki = k / 3, kj = k % 3;
    int hp = h + (ki - 1) * dd;
    if (hp < 0 || hp >= 64) {           // whole row OOB vertically: constant contribution
      const float* c0p = C0 + (br * 9 + k) * 64 + o0;
      float c0v[4] = {c0p[0], c0p[1], c0p[2], c0p[3]};
#pragma unroll
      for (int i = 0; i < 4; ++i)
#pragma unroll
        for (int j = 0; j < 4; ++j) acc[i][j] += c0v[j];
      continue;
    }
    const __hip_bfloat16* rowp = F + (size_t)(b * 64 + hp) * KC * WP + kj * dd;
    const float* wrow = Wt + (size_t)k * KC * 64;
    for (int t = 0; t < CF; ++t) {
      int ic0 = t * 64;
#pragma unroll
      for (int m = 0; m < 16; ++m) {    // stage 64x64 A (bf16->f32) and 64x64 W
        int lin = tid + m * 256;
        int ict = lin >> 6, wl = lin & 63;
        As[ict][wl] = __bfloat162float(rowp[(size_t)(ic0 + ict) * WP + wl]);
        Ws[ict][wl] = wrow[(ic0 + ict) * 64 + wl];
      }
      __syncthreads();
#pragma unroll 8
      for (int ict = 0; ict < 64; ++ict) {
        float4 a  = *reinterpret_cast<const float4*>(&As[ict][w0]);
        float4 wv = *reinterpret_cast<const float4*>(&Ws[ict][o0]);
        acc[0][0] += a.x * wv.x; acc[0][1] += a.x * wv.y; acc[0][2] += a.x * wv.z; acc[0][3] += a.x * wv.w;
        acc[1][0] += a.y * wv.x; acc[1][1] += a.y * wv.y; acc[1][2] += a.y * wv.z; acc[1][3] += a.y * wv.w;
        acc[2][0] += a.z * wv.x; acc[2][1] += a.z * wv.y; acc[2][2] += a.z * wv.z; acc[2][3] += a.z * wv.w;
        acc[3][0] += a.w * wv.x; acc[3][1] += a.w * wv.y; acc[3][2] += a.w * wv.z; acc[3][3] += a.w * wv.w;
      }
      __syncthreads();
    }
  }
  float* yp = y + (size_t)((br * 2 + b) * 64 + h) * 4096;
#pragma unroll
  for (int j = 0; j < 4; ++j) {
    float4 v = make_float4(acc[0][j], acc[1][j], acc[2][j], acc[3][j]);
    *reinterpret_cast<float4*>(&yp[(o0 + j) * 64 + w0]) = v;
  }
}

// ---------- per-branch BN stats over (b,h,w) ----------
__global__ void bnstats_k(const float* __restrict__ y, float* __restrict__ bnm,
                          float* __restrict__ bnv) {
  int br = blockIdx.x >> 6, o = blockIdx.x & 63;
  float s = 0.0f, q = 0.0f;
  for (int idx = threadIdx.x; idx < POS; idx += 256) {
    int b = idx >> 12, h = (idx >> 6) & 63, w = idx & 63;
    float v = y[(size_t)(br * 2 + b) * 262144 + (size_t)h * 4096 + o * 64 + w];
    s += v; q += v * v;
  }
  __shared__ float sb[4];
  s = block_reduce_256(s, sb);
  q = block_reduce_256(q, sb);
  if (threadIdx.x == 0) {
    float m = s * (1.0f / POS);
    bnm[br * 64 + o] = m;
    bnv[br * 64 + o] = q * (1.0f / POS) - m * m;
  }
}

// ---------- SE pre-mean: mean over (h,w) of relu(bn(y)) ----------
__global__ void sesum_k(const float* __restrict__ y, const float* __restrict__ bnm,
                        const float* __restrict__ bnv,
                        const float* g0, const float* b0p, const float* g1, const float* b1p,
                        const float* g2, const float* b2p, float* __restrict__ se_mean) {
  int blk = blockIdx.x;                 // [0,384)
  int br = blk >> 7, rem = blk & 127, b = rem >> 6, o = rem & 63;
  const float* gptr = (br == 0) ? g0 : ((br == 1) ? g1 : g2);
  const float* bptr = (br == 0) ? b0p : ((br == 1) ? b1p : b2p);
  float m = bnm[br * 64 + o], var = bnv[br * 64 + o];
  float kk = gptr[o] / sqrtf(var + 1e-5f);
  float cc = bptr[o] - m * kk;
  const float* yp = y + (size_t)(br * 2 + b) * 262144 + o * 64;
  float s = 0.0f;
  for (int idx = threadIdx.x; idx < HW; idx += 256) {
    int h = idx >> 6, w = idx & 63;
    float a = yp[(size_t)h * 4096 + w] * kk + cc;
    s += (a > 0.0f) ? a : 0.0f;
  }
  __shared__ float sb[4];
  s = block_reduce_256(s, sb);
  if (threadIdx.x == 0) se_mean[(br * 2 + b) * 64 + o] = s * (1.0f / HW);
}

// ---------- SE MLP + fold BN+SE into per-(b,channel) affine A1,A0 ----------
__global__ void semlp_k(const float* __restrict__ se_mean,
                        const float* __restrict__ bnm, const float* __restrict__ bnv,
                        const float* g0, const float* b0p, const float* g1, const float* b1p,
                        const float* g2, const float* b2p,
                        const float* w10, const float* w11, const float* w12,
                        const float* w20, const float* w21, const float* w22,
                        float* __restrict__ A1, float* __restrict__ A0) {
  int bb = blockIdx.x;                  // br*2 + b, [0,6)
  int br = bb >> 1;
  int o = threadIdx.x;                  // 64 threads
  const float* w1 = (br == 0) ? w10 : ((br == 1) ? w11 : w12);
  const float* w2 = (br == 0) ? w20 : ((br == 1) ? w21 : w22);
  const float* gptr = (br == 0) ? g0 : ((br == 1) ? g1 : g2);
  const float* bptr = (br == 0) ? b0p : ((br == 1) ? b1p : b2p);
  __shared__ float sm[64];
  sm[o] = se_mean[bb * 64 + o];
  __syncthreads();
  float z[4];
#pragma unroll
  for (int j = 0; j < 4; ++j) {
    float s = 0.0f;
    for (int c2 = 0; c2 < 64; ++c2) s += sm[c2] * w1[j * 64 + c2];
    z[j] = (s > 0.0f) ? s : 0.0f;
  }
  float t = 0.0f;
#pragma unroll
  for (int j = 0; j < 4; ++j) t += z[j] * w2[o * 4 + j];
  t = sigmoidf_(t);
  float m = bnm[br * 64 + o], var = bnv[br * 64 + o];
  float kk = gptr[o] / sqrtf(var + 1e-5f);
  float cc = bptr[o] - m * kk;
  A1[bb * 64 + o] = kk * t;             // relu(x)*t == relu(x*t) since t>0
  A0[bb * 64 + o] = cc * t;
}

// ---------- global-pool branch folded into fuse_gp[b][o2] ----------
__global__ void gp_k(const float* __restrict__ xm, const float* __restrict__ gw,
                     const float* __restrict__ gb, const float* __restrict__ bng,
                     const float* __restrict__ bnb, const float* __restrict__ w1,
                     const float* __restrict__ w2, const float* __restrict__ fuse_w,
                     float* __restrict__ fuse_gp) {
  int tid = threadIdx.x;                // 128 threads
  int b = tid >> 6, o = tid & 63;
  __shared__ float g0s[2][64], gp1s[2][64], gpvs[2][64];
  float g0 = gb[o];
  for (int i = 0; i < 64; ++i) g0 += xm[b * 64 + i] * gw[o * 64 + i];
  g0s[b][o] = g0;
  __syncthreads();
  float mu = 0.5f * (g0s[0][o] + g0s[1][o]);
  float df = g0s[0][o] - g0s[1][o];
  float var = 0.25f * df * df;          // exact population var for N=2
  float v = (g0 - mu) / sqrtf(var + 1e-5f) * bng[o] + bnb[o];
  v = (v > 0.0f) ? v : 0.0f;
  gp1s[b][o] = v;
  __syncthreads();
  float z[4];
#pragma unroll
  for (int j = 0; j < 4; ++j) {
    float s = 0.0f;
    for (int c2 = 0; c2 < 64; ++c2) s += gp1s[b][c2] * w1[j * 64 + c2];
    z[j] = (s > 0.0f) ? s : 0.0f;
  }
  float t = 0.0f;
#pragma unroll
  for (int j = 0; j < 4; ++j) t += z[j] * w2[o * 4 + j];
  t = sigmoidf_(t);
  gpvs[b][o] = v * t;
  __syncthreads();
  float fg = 0.0f;
  for (int c2 = 0; c2 < 64; ++c2) fg += fuse_w[o * 256 + 192 + c2] * gpvs[b][c2];
  fuse_gp[b * 64 + o] = fg;
}

// ---------- fuse_w transpose (branch part): fwT[i][o] ----------
__global__ void fusewt_k(const float* __restrict__ fw, float* __restrict__ fwT) {
  int lin = blockIdx.x * 256 + threadIdx.x;  // [0, 192*64)
  int o = lin & 63, i2 = lin >> 6;
  fwT[i2 * 64 + o] = fw[o * 256 + i2];
}

// ---------- fuse GEMM: tmp[b][h][o][w] ----------
__global__ __launch_bounds__(256) void fuse_k(
    const float* __restrict__ y, const float* __restrict__ A1, const float* __restrict__ A0,
    const float* __restrict__ fwT, const float* __restrict__ fb, const float* __restrict__ fgp,
    float* __restrict__ tmp) {
  int bid = blockIdx.x;                 // [0,128): b*64+h
  int b = bid >> 6, h = bid & 63;
  int tid = threadIdx.x;
  int wg = tid & 15, og = tid >> 4;
  int w0 = wg * 4, o0 = og * 4;
  float acc[4][4] = {};
  __shared__ float As[64][64];
  __shared__ float Ws[64][64];
  for (int br = 0; br < 3; ++br) {
#pragma unroll
    for (int m = 0; m < 16; ++m) {
      int lin = tid + m * 256;
      int oc = lin >> 6, wl = lin & 63;
      float v = y[(size_t)(br * 2 + b) * 262144 + (size_t)h * 4096 + oc * 64 + wl];
      float a1 = A1[(br * 2 + b) * 64 + oc], a0 = A0[(br * 2 + b) * 64 + oc];
      v = v * a1 + a0;
      As[oc][wl] = (v > 0.0f) ? v : 0.0f;
      Ws[oc][wl] = fwT[(br * 64 + oc) * 64 + wl];
    }
    __syncthreads();
#pragma unroll 8
    for (int ict = 0; ict < 64; ++ict) {
      float4 a  = *reinterpret_cast<const float4*>(&As[ict][w0]);
      float4 wv = *reinterpret_cast<const float4*>(&Ws[ict][o0]);
      acc[0][0] += a.x * wv.x; acc[0][1] += a.x * wv.y; acc[0][2] += a.x * wv.z; acc[0][3] += a.x * wv.w;
      acc[1][0] += a.y * wv.x; acc[1][1] += a.y * wv.y; acc[1][2] += a.y * wv.z; acc[1][3] += a.y * wv.w;
      acc[2][0] += a.z * wv.x; acc[2][1] += a.z * wv.y; acc[2][2] += a.z * wv.z; acc[2][3] += a.z * wv.w;
      acc[3][0] += a.w * wv.x; acc[3][1] += a.w * wv.y; acc[3][2] += a.w * wv.z; acc[3][3] += a.w * wv.w;
    }
    __syncthreads();
  }
  float* tp = tmp + (size_t)(b * 64 + h) * 4096;
#pragma unroll
  for (int j = 0; j < 4; ++j) {
    float bias = fb[o0 + j] + fgp[b * 64 + o0 + j];
    float4 v = make_float4(acc[0][j] + bias, acc[1][j] + bias, acc[2][j] + bias, acc[3][j] + bias);
    *reinterpret_cast<float4*>(&tp[(o0 + j) * 64 + w0]) = v;
  }
}

// ---------- fuse BN stats ----------
__global__ void fstats_k(const float* __restrict__ tmp, float* __restrict__ fm,
                         float* __restrict__ fv) {
  int o = blockIdx.x;                   // [0,64)
  float s = 0.0f, q = 0.0f;
  for (int idx = threadIdx.x; idx < POS; idx += 256) {
    int bh = idx >> 6, w = idx & 63;
    float v = tmp[(size_t)bh * 4096 + o * 64 + w];
    s += v; q += v * v;
  }
  __shared__ float sb[4];
  s = block_reduce_256(s, sb);
  q = block_reduce_256(q, sb);
  if (threadIdx.x == 0) {
    float m = s * (1.0f / POS);
    fm[o] = m;
    fv[o] = q * (1.0f / POS) - m * m;
  }
}

// ---------- final BN+relu, write (B,Co,H,W) ----------
__global__ void final_k(const float* __restrict__ tmp, const float* __restrict__ fm,
                        const float* __restrict__ fv, const float* __restrict__ g,
                        const float* __restrict__ bb, float* __restrict__ out) {
  int lin = blockIdx.x * 256 + threadIdx.x;  // [0, 524288)
  int w = lin & 63, h2 = (lin >> 6) & 63, o = (lin >> 12) & 63, b = lin >> 18;
  float v = tmp[((size_t)(b * 64 + h2) * 64 + o) * 64 + w];
  float kk = g[o] / sqrtf(fv[o] + 1e-5f);
  float r = (v - fm[o]) * kk + bb[o];
  out[lin] = (r > 0.0f) ? r : 0.0f;
}

extern "C" void kernel_launch(void* const* d_in, const int* in_sizes, int n_in,
                              void* d_out, int out_size, void* d_ws, size_t ws_size,
                              hipStream_t stream) {
  const float* x = (const float*)d_in[0];
  const float* base_w[3]   = {(const float*)d_in[1],  (const float*)d_in[7],  (const float*)d_in[13]};
  const float* spline_w[3] = {(const float*)d_in[2],  (const float*)d_in[8],  (const float*)d_in[14]};
  const float* bn_g[3]     = {(const float*)d_in[3],  (const float*)d_in[9],  (const float*)d_in[15]};
  const float* bn_b[3]     = {(const float*)d_in[4],  (const float*)d_in[10], (const float*)d_in[16]};
  const float* se_w1[3]    = {(const float*)d_in[5],  (const float*)d_in[11], (const float*)d_in[17]};
  const float* se_w2[3]    = {(const float*)d_in[6],  (const float*)d_in[12], (const float*)d_in[18]};
  const float* gp_conv_w = (const float*)d_in[19];
  const float* gp_conv_b = (const float*)d_in[20];
  const float* gp_bn_g   = (const float*)d_in[21];
  const float* gp_bn_b   = (const float*)d_in[22];
  const float* gp_se_w1  = (const float*)d_in[23];
  const float* gp_se_w2  = (const float*)d_in[24];
  const float* fuse_w    = (const float*)d_in[25];
  const float* fuse_b    = (const float*)d_in[26];
  const float* fuse_bn_g = (const float*)d_in[27];
  const float* fuse_bn_b = (const float*)d_in[28];
  float* out = (float*)d_out;

  char* wsp = (char*)d_ws;
  auto alloc = [&](size_t bytes) -> char* {
    char* p = wsp;
    wsp += (bytes + 255) & ~(size_t)255;
    return p;
  };
  __hip_bfloat16* F0 = (__hip_bfloat16*)alloc((size_t)4358144 * 2);   // 2*64*448*76
  __hip_bfloat16* F1 = (__hip_bfloat16*)alloc((size_t)7208960 * 2);   // 2*64*640*88
  __hip_bfloat16* F2 = (__hip_bfloat16*)alloc((size_t)10649600 * 2);  // 2*64*832*100
  float* Wt0 = (float*)alloc((size_t)258048 * 4);
  float* Wt1 = (float*)alloc((size_t)368640 * 4);
  float* Wt2 = (float*)alloc((size_t)479232 * 4);
  float* C0v = (float*)alloc((size_t)1728 * 4);
  float* y   = (float*)alloc((size_t)1572864 * 4);                    // [3][2][64][64(o)][64(w)] by row h
  float* bnm = (float*)alloc(192 * 4);
  float* bnv = (float*)alloc(192 * 4);
  float* se_mean = (float*)alloc(384 * 4);
  float* A1  = (float*)alloc(384 * 4);
  float* A0  = (float*)alloc(384 * 4);
  float* xm  = (float*)alloc(128 * 4);
  float* fgp = (float*)alloc(128 * 4);
  float* fwT = (float*)alloc((size_t)12288 * 4);
  float* tmp = (float*)alloc((size_t)524288 * 4);
  float* fm  = (float*)alloc(64 * 4);
  float* fv  = (float*)alloc(64 * 4);

  features_k<3, 6><<<2048, 256, 0, stream>>>(x, F0);
  features_k<6, 12><<<2048, 256, 0, stream>>>(x, F1);
  features_k<9, 18><<<2048, 256, 0, stream>>>(x, F2);

  wprep_k<<<1008, 256, 0, stream>>>(base_w[0], spline_w[0], Wt0, 6, 448);
  wprep_k<<<1440, 256, 0, stream>>>(base_w[1], spline_w[1], Wt1, 9, 640);
  wprep_k<<<1872, 256, 0, stream>>>(base_w[2], spline_w[2], Wt2, 12, 832);

  c0_k<3><<<9, 64, 0, stream>>>(Wt0, C0v, 0);
  c0_k<6><<<9, 64, 0, stream>>>(Wt1, C0v, 9);
  c0_k<9><<<9, 64, 0, stream>>>(Wt2, C0v, 18);

  xmean_k<<<128, 256, 0, stream>>>(x, xm);

  conv_k<<<384, 256, 0, stream>>>(F0, F1, F2, Wt0, Wt1, Wt2, C0v, y);

  bnstats_k<<<192, 256, 0, stream>>>(y, bnm, bnv);
  sesum_k<<<384, 256, 0, stream>>>(y, bnm, bnv, bn_g[0], bn_b[0], bn_g[1], bn_b[1],
                                   bn_g[2], bn_b[2], se_mean);
  semlp_k<<<6, 64, 0, stream>>>(se_mean, bnm, bnv, bn_g[0], bn_b[0], bn_g[1], bn_b[1],
                                bn_g[2], bn_b[2], se_w1[0], se_w1[1], se_w1[2],
                                se_w2[0], se_w2[1], se_w2[2], A1, A0);
  gp_k<<<1, 128, 0, stream>>>(xm, gp_conv_w, gp_conv_b, gp_bn_g, gp_bn_b, gp_se_w1,
                              gp_se_w2, fuse_w, fgp);
  fusewt_k<<<48, 256, 0, stream>>>(fuse_w, fwT);
  fuse_k<<<128, 256, 0, stream>>>(y, A1, A0, fwT, fuse_b, fgp, tmp);
  fstats_k<<<64, 256, 0, stream>>>(tmp, fm, fv);
  final_k<<<2048, 256, 0, stream>>>(tmp, fm, fv, fuse_bn_g, fuse_bn_b, out);
}

// Round 2
// 469.070 us; speedup vs baseline: 1.7893x; 1.7893x over previous
//
#include <hip/hip_runtime.h>
#include <hip/hip_bf16.h>
#include <math.h>

#define DEV __device__ __forceinline__

static constexpr int HW  = 4096;    // H*W
static constexpr int POS = 8192;    // B*H*W
static constexpr int SLAB = 6 * 64 * 4096;  // one ksplit partial slab (floats)

typedef __attribute__((ext_vector_type(8)))  short short8;
typedef __attribute__((ext_vector_type(16))) float floatx16;

// ---------- B-spline basis (order 3), mirrors reference Cox-de Boor ----------
template<int G>
DEV void bsplines(float x, float* out /* G+3 values */) {
  const float h = 2.0f / (float)G;
  float knot[G + 7];
#pragma unroll
  for (int t = 0; t < G + 7; ++t) knot[t] = -1.0f + (float)(t - 3) * h;
  float bb[G + 6];
#pragma unroll
  for (int t = 0; t < G + 6; ++t) bb[t] = (x >= knot[t] && x < knot[t + 1]) ? 1.0f : 0.0f;
#pragma unroll
  for (int j = 1; j <= 3; ++j) {
#pragma unroll
    for (int t = 0; t < G + 6 - j; ++t) {
      float left  = (x - knot[t]) / (knot[t + j] - knot[t]);
      float right = (knot[t + j + 1] - x) / (knot[t + j + 1] - knot[t + 1]);
      bb[t] = left * bb[t] + right * bb[t + 1];
    }
  }
#pragma unroll
  for (int t = 0; t < G + 3; ++t) out[t] = bb[t];
}

DEV float sigmoidf_(float x) { return 1.0f / (1.0f + __expf(-x)); }

DEV float block_reduce_256(float v, float* sb) {  // blockDim.x == 256
  __syncthreads();
#pragma unroll
  for (int off = 32; off > 0; off >>= 1) v += __shfl_down(v, off, 64);
  int lane = threadIdx.x & 63, wid = threadIdx.x >> 6;
  if (lane == 0) sb[wid] = v;
  __syncthreads();
  return sb[0] + sb[1] + sb[2] + sb[3];
}

// ---------- features: F[b][h][wp][ic], ic = i*CF + c (K-contiguous), w padded ----------
template<int G, int D>
__global__ void features_k(const float* __restrict__ x, __hip_bfloat16* __restrict__ F) {
  constexpr int CF = G + 4;
  constexpr int NB = G + 3;
  constexpr int WP = 64 + 2 * D;
  constexpr int KC = 64 * CF;
  int lin = blockIdx.x * 256 + threadIdx.x;  // (b,i,h,wp), wp innermost: 2*64*64*WP exact
  int wp = lin % WP;
  int rest = lin / WP;
  int h = rest & 63, i = (rest >> 6) & 63, b = rest >> 12;
  int w = wp - D;
  float xv = (w >= 0 && w < 64) ? x[((size_t)(b * 64 + i) * 64 + h) * 64 + w] : 0.0f;
  float s = xv * sigmoidf_(xv);
  float bas[NB];
  bsplines<G>(xv, bas);
  __hip_bfloat16* Fp = F + ((size_t)((b * 64 + h) * WP + wp)) * KC + i * CF;
  Fp[0] = __float2bfloat16(s);
#pragma unroll
  for (int c = 1; c < CF; ++c) Fp[c] = __float2bfloat16(bas[c - 1]);
}

// ---------- weight repack: Wt[tap][o][ic] bf16, ic = i*CF + c ----------
template<int CF>
__global__ void wprep_k(const float* __restrict__ base_w, const float* __restrict__ spline_w,
                        __hip_bfloat16* __restrict__ Wt) {
  constexpr int KC = 64 * CF, NB = CF - 1 - 3 + 3;  // NB = CF-1
  int lin = blockIdx.x * 256 + threadIdx.x;  // (tap, o, ic), 9*64*KC exact
  int ic = lin % KC;
  int rest = lin / KC;
  int o = rest & 63, tap = rest >> 6;
  int c = ic % CF, i = ic / CF;
  float v = (c == 0) ? base_w[(o * 64 + i) * 9 + tap]
                     : spline_w[((o * 64 + i) * 9 + tap) * (CF - 1) + (c - 1)];
  Wt[lin] = __float2bfloat16(v);
}

// ---------- C0r[ki][o]: sum over kj of fully-OOB-row tap contribution ----------
template<int G>
__global__ void c0r_k(const __hip_bfloat16* __restrict__ Wt, float* __restrict__ C0r, int broff) {
  constexpr int NB = G + 3, CF = G + 4, KC = 64 * CF;
  int ki = blockIdx.x, o = threadIdx.x;
  float b0[NB];
  bsplines<G>(0.0f, b0);
  float sum = 0.0f;
  for (int kj = 0; kj < 3; ++kj) {
    const __hip_bfloat16* p = Wt + (size_t)((ki * 3 + kj) * 64 + o) * KC;
    for (int i = 0; i < 64; ++i)
#pragma unroll
      for (int c = 1; c < CF; ++c) sum += __bfloat162float(p[i * CF + c]) * b0[c - 1];
  }
  C0r[broff + ki * 64 + o] = sum;
}

// ---------- x mean over (H,W) per (b,i) ----------
__global__ void xmean_k(const float* __restrict__ x, float* __restrict__ xm) {
  int bi = blockIdx.x;  // [0,128)
  const float* p = x + (size_t)bi * HW;
  float s = 0.0f;
  for (int t = threadIdx.x; t < HW; t += 256) s += p[t];
  __shared__ float sb[4];
  s = block_reduce_256(s, sb);
  if (threadIdx.x == 0) xm[bi] = s * (1.0f / HW);
}

// ---------- KAN conv via MFMA: per-branch device body ----------
// Wave tile: 64(o) x 64(w) for one output row h, one ki (3 kj taps, K = 3*KC).
// ypart[ki][br*2+b][h][o][w] partial sums (reduced in bnstats_k).
template<int CF, int DD>
DEV void conv_dev(int bid, const short* __restrict__ F, const short* __restrict__ W,
                  const float* __restrict__ C0r, float* __restrict__ ypart, int br) {
  constexpr int KC = 64 * CF;
  constexpr int WP = 64 + 2 * DD;
  constexpr int KSTEPS = KC / 16;
  int ht = bid & 31;             // h-pair
  int b  = (bid >> 5) & 1;
  int ki = bid >> 6;             // 0..2
  int wv = threadIdx.x >> 6;     // wave: one h row
  int lane = threadIdx.x & 63;
  int lr = lane & 31, lq = lane >> 5;

  int h = ht * 2 + wv;
  int hs = h + (ki - 1) * DD;
  bool valid = (hs >= 0 && hs < 64);

  float* yb = ypart + (size_t)ki * SLAB + ((size_t)((br * 2 + b) * 64 + h)) * 4096;

  if (!valid) {                  // whole-row OOB: constant contribution only
    const float* c0 = C0r + (br * 3 + ki) * 64;
#pragma unroll
    for (int ot = 0; ot < 2; ++ot)
#pragma unroll
      for (int wh = 0; wh < 2; ++wh) {
        int w = wh * 32 + lr;
#pragma unroll
        for (int reg = 0; reg < 16; ++reg) {
          int o = (reg & 3) + 8 * (reg >> 2) + 4 * lq + 32 * ot;
          yb[(size_t)o * 64 + w] = c0[o];
        }
      }
    return;
  }

  floatx16 acc[2][2];
#pragma unroll
  for (int ot = 0; ot < 2; ++ot)
#pragma unroll
    for (int wh = 0; wh < 2; ++wh)
#pragma unroll
      for (int r = 0; r < 16; ++r) acc[ot][wh][r] = 0.0f;

  const short* rowF = F + ((size_t)(b * 64 + hs) * WP) * KC;

  for (int kj = 0; kj < 3; ++kj) {
    const short* wb = W + (size_t)((ki * 3 + kj) * 64 + lr) * KC + lq * 8;
    const short* fb0 = rowF + (size_t)(kj * DD + lr) * KC + lq * 8;
    const short* fb1 = fb0 + (size_t)32 * KC;
#pragma unroll 4
    for (int kk = 0; kk < KSTEPS; ++kk) {
      short8 a0 = *(const short8*)(wb + kk * 16);
      short8 a1 = *(const short8*)(wb + (size_t)32 * KC + kk * 16);
      short8 b0 = *(const short8*)(fb0 + kk * 16);
      short8 b1 = *(const short8*)(fb1 + kk * 16);
      acc[0][0] = __builtin_amdgcn_mfma_f32_32x32x16_bf16(a0, b0, acc[0][0], 0, 0, 0);
      acc[0][1] = __builtin_amdgcn_mfma_f32_32x32x16_bf16(a0, b1, acc[0][1], 0, 0, 0);
      acc[1][0] = __builtin_amdgcn_mfma_f32_32x32x16_bf16(a1, b0, acc[1][0], 0, 0, 0);
      acc[1][1] = __builtin_amdgcn_mfma_f32_32x32x16_bf16(a1, b1, acc[1][1], 0, 0, 0);
    }
  }

#pragma unroll
  for (int ot = 0; ot < 2; ++ot)
#pragma unroll
    for (int wh = 0; wh < 2; ++wh) {
      int w = wh * 32 + lr;
#pragma unroll
      for (int reg = 0; reg < 16; ++reg) {
        int o = (reg & 3) + 8 * (reg >> 2) + 4 * lq + 32 * ot;
        yb[(size_t)o * 64 + w] = acc[ot][wh][reg];
      }
    }
}

__global__ __launch_bounds__(128) void conv_all_k(
    const short* __restrict__ F0, const short* __restrict__ F1, const short* __restrict__ F2,
    const short* __restrict__ W0, const short* __restrict__ W1, const short* __restrict__ W2,
    const float* __restrict__ C0r, float* __restrict__ ypart) {
  int br = blockIdx.x / 192;
  int bid = blockIdx.x % 192;
  if (br == 0)      conv_dev<7, 6>(bid, F0, W0, C0r, ypart, 0);
  else if (br == 1) conv_dev<10, 12>(bid, F1, W1, C0r, ypart, 1);
  else              conv_dev<13, 18>(bid, F2, W2, C0r, ypart, 2);
}

// ---------- reduce 3 k-split partials into slab0 + per-branch BN stats ----------
__global__ void bnstats_k(float* __restrict__ yp, float* __restrict__ bnm,
                          float* __restrict__ bnv) {
  int br = blockIdx.x >> 6, o = blockIdx.x & 63;
  float s = 0.0f, q = 0.0f;
  for (int idx = threadIdx.x; idx < POS; idx += 256) {
    int b = idx >> 12, h = (idx >> 6) & 63, w = idx & 63;
    size_t base = ((size_t)((br * 2 + b) * 64 + h)) * 4096 + o * 64 + w;
    float v = yp[base] + yp[base + SLAB] + yp[base + 2 * (size_t)SLAB];
    yp[base] = v;
    s += v; q += v * v;
  }
  __shared__ float sb[4];
  s = block_reduce_256(s, sb);
  q = block_reduce_256(q, sb);
  if (threadIdx.x == 0) {
    float m = s * (1.0f / POS);
    bnm[br * 64 + o] = m;
    bnv[br * 64 + o] = q * (1.0f / POS) - m * m;
  }
}

// ---------- SE pre-mean: mean over (h,w) of relu(bn(y)) ----------
__global__ void sesum_k(const float* __restrict__ y, const float* __restrict__ bnm,
                        const float* __restrict__ bnv,
                        const float* g0, const float* b0p, const float* g1, const float* b1p,
                        const float* g2, const float* b2p, float* __restrict__ se_mean) {
  int blk = blockIdx.x;  // [0,384)
  int br = blk >> 7, rem = blk & 127, b = rem >> 6, o = rem & 63;
  const float* gptr = (br == 0) ? g0 : ((br == 1) ? g1 : g2);
  const float* bptr = (br == 0) ? b0p : ((br == 1) ? b1p : b2p);
  float m = bnm[br * 64 + o], var = bnv[br * 64 + o];
  float kk = gptr[o] / sqrtf(var + 1e-5f);
  float cc = bptr[o] - m * kk;
  const float* yp = y + (size_t)(br * 2 + b) * 262144 + o * 64;
  float s = 0.0f;
  for (int idx = threadIdx.x; idx < HW; idx += 256) {
    int h = idx >> 6, w = idx & 63;
    float a = yp[(size_t)h * 4096 + w] * kk + cc;
    s += (a > 0.0f) ? a : 0.0f;
  }
  __shared__ float sb[4];
  s = block_reduce_256(s, sb);
  if (threadIdx.x == 0) se_mean[(br * 2 + b) * 64 + o] = s * (1.0f / HW);
}

// ---------- SE MLP + fold BN+SE into per-(b,channel) affine A1,A0 ----------
__global__ void semlp_k(const float* __restrict__ se_mean,
                        const float* __restrict__ bnm, const float* __restrict__ bnv,
                        const float* g0, const float* b0p, const float* g1, const float* b1p,
                        const float* g2, const float* b2p,
                        const float* w10, const float* w11, const float* w12,
                        const float* w20, const float* w21, const float* w22,
                        float* __restrict__ A1, float* __restrict__ A0) {
  int bb = blockIdx.x;  // br*2 + b, [0,6)
  int br = bb >> 1;
  int o = threadIdx.x;  // 64 threads
  const float* w1 = (br == 0) ? w10 : ((br == 1) ? w11 : w12);
  const float* w2 = (br == 0) ? w20 : ((br == 1) ? w21 : w22);
  const float* gptr = (br == 0) ? g0 : ((br == 1) ? g1 : g2);
  const float* bptr = (br == 0) ? b0p : ((br == 1) ? b1p : b2p);
  __shared__ float sm[64];
  sm[o] = se_mean[bb * 64 + o];
  __syncthreads();
  float z[4];
#pragma unroll
  for (int j = 0; j < 4; ++j) {
    float s = 0.0f;
    for (int c2 = 0; c2 < 64; ++c2) s += sm[c2] * w1[j * 64 + c2];
    z[j] = (s > 0.0f) ? s : 0.0f;
  }
  float t = 0.0f;
#pragma unroll
  for (int j = 0; j < 4; ++j) t += z[j] * w2[o * 4 + j];
  t = sigmoidf_(t);
  float m = bnm[br * 64 + o], var = bnv[br * 64 + o];
  float kk = gptr[o] / sqrtf(var + 1e-5f);
  float cc = bptr[o] - m * kk;
  A1[bb * 64 + o] = kk * t;  // relu(x)*t == relu(x*t) since t>0
  A0[bb * 64 + o] = cc * t;
}

// ---------- global-pool branch folded into fuse_gp[b][o2] ----------
__global__ void gp_k(const float* __restrict__ xm, const float* __restrict__ gw,
                     const float* __restrict__ gb, const float* __restrict__ bng,
                     const float* __restrict__ bnb, const float* __restrict__ w1,
                     const float* __restrict__ w2, const float* __restrict__ fuse_w,
                     float* __restrict__ fuse_gp) {
  int tid = threadIdx.x;  // 128 threads
  int b = tid >> 6, o = tid & 63;
  __shared__ float g0s[2][64], gp1s[2][64], gpvs[2][64];
  float g0 = gb[o];
  for (int i = 0; i < 64; ++i) g0 += xm[b * 64 + i] * gw[o * 64 + i];
  g0s[b][o] = g0;
  __syncthreads();
  float mu = 0.5f * (g0s[0][o] + g0s[1][o]);
  float df = g0s[0][o] - g0s[1][o];
  float var = 0.25f * df * df;  // exact population var for N=2
  float v = (g0 - mu) / sqrtf(var + 1e-5f) * bng[o] + bnb[o];
  v = (v > 0.0f) ? v : 0.0f;
  gp1s[b][o] = v;
  __syncthreads();
  float z[4];
#pragma unroll
  for (int j = 0; j < 4; ++j) {
    float s = 0.0f;
    for (int c2 = 0; c2 < 64; ++c2) s += gp1s[b][c2] * w1[j * 64 + c2];
    z[j] = (s > 0.0f) ? s : 0.0f;
  }
  float t = 0.0f;
#pragma unroll
  for (int j = 0; j < 4; ++j) t += z[j] * w2[o * 4 + j];
  t = sigmoidf_(t);
  gpvs[b][o] = v * t;
  __syncthreads();
  float fg = 0.0f;
  for (int c2 = 0; c2 < 64; ++c2) fg += fuse_w[o * 256 + 192 + c2] * gpvs[b][c2];
  fuse_gp[b * 64 + o] = fg;
}

// ---------- fuse_w transpose (branch part): fwT[i][o] ----------
__global__ void fusewt_k(const float* __restrict__ fw, float* __restrict__ fwT) {
  int lin = blockIdx.x * 256 + threadIdx.x;  // [0, 192*64)
  int o = lin & 63, i2 = lin >> 6;
  fwT[i2 * 64 + o] = fw[o * 256 + i2];
}

// ---------- fuse GEMM: tmp[b][h][o][w] ----------
__global__ __launch_bounds__(256) void fuse_k(
    const float* __restrict__ y, const float* __restrict__ A1, const float* __restrict__ A0,
    const float* __restrict__ fwT, const float* __restrict__ fb, const float* __restrict__ fgp,
    float* __restrict__ tmp) {
  int bid = blockIdx.x;  // [0,128): b*64+h
  int b = bid >> 6, h = bid & 63;
  int tid = threadIdx.x;
  int wg = tid & 15, og = tid >> 4;
  int w0 = wg * 4, o0 = og * 4;
  float acc[4][4] = {};
  __shared__ float As[64][64];
  __shared__ float Ws[64][64];
  for (int br = 0; br < 3; ++br) {
#pragma unroll
    for (int m = 0; m < 16; ++m) {
      int lin = tid + m * 256;
      int oc = lin >> 6, wl = lin & 63;
      float v = y[(size_t)(br * 2 + b) * 262144 + (size_t)h * 4096 + oc * 64 + wl];
      float a1 = A1[(br * 2 + b) * 64 + oc], a0 = A0[(br * 2 + b) * 64 + oc];
      v = v * a1 + a0;
      As[oc][wl] = (v > 0.0f) ? v : 0.0f;
      Ws[oc][wl] = fwT[(br * 64 + oc) * 64 + wl];
    }
    __syncthreads();
#pragma unroll 8
    for (int ict = 0; ict < 64; ++ict) {
      float4 a  = *reinterpret_cast<const float4*>(&As[ict][w0]);
      float4 wv = *reinterpret_cast<const float4*>(&Ws[ict][o0]);
      acc[0][0] += a.x * wv.x; acc[0][1] += a.x * wv.y; acc[0][2] += a.x * wv.z; acc[0][3] += a.x * wv.w;
      acc[1][0] += a.y * wv.x; acc[1][1] += a.y * wv.y; acc[1][2] += a.y * wv.z; acc[1][3] += a.y * wv.w;
      acc[2][0] += a.z * wv.x; acc[2][1] += a.z * wv.y; acc[2][2] += a.z * wv.z; acc[2][3] += a.z * wv.w;
      acc[3][0] += a.w * wv.x; acc[3][1] += a.w * wv.y; acc[3][2] += a.w * wv.z; acc[3][3] += a.w * wv.w;
    }
    __syncthreads();
  }
  float* tp = tmp + (size_t)(b * 64 + h) * 4096;
#pragma unroll
  for (int j = 0; j < 4; ++j) {
    float bias = fb[o0 + j] + fgp[b * 64 + o0 + j];
    float4 v = make_float4(acc[0][j] + bias, acc[1][j] + bias, acc[2][j] + bias, acc[3][j] + bias);
    *reinterpret_cast<float4*>(&tp[(o0 + j) * 64 + w0]) = v;
  }
}

// ---------- fuse BN stats ----------
__global__ void fstats_k(const float* __restrict__ tmp, float* __restrict__ fm,
                         float* __restrict__ fv) {
  int o = blockIdx.x;  // [0,64)
  float s = 0.0f, q = 0.0f;
  for (int idx = threadIdx.x; idx < POS; idx += 256) {
    int bh = idx >> 6, w = idx & 63;
    float v = tmp[(size_t)bh * 4096 + o * 64 + w];
    s += v; q += v * v;
  }
  __shared__ float sb[4];
  s = block_reduce_256(s, sb);
  q = block_reduce_256(q, sb);
  if (threadIdx.x == 0) {
    float m = s * (1.0f / POS);
    fm[o] = m;
    fv[o] = q * (1.0f / POS) - m * m;
  }
}

// ---------- final BN+relu, write (B,Co,H,W) ----------
__global__ void final_k(const float* __restrict__ tmp, const float* __restrict__ fm,
                        const float* __restrict__ fv, const float* __restrict__ g,
                        const float* __restrict__ bb, float* __restrict__ out) {
  int lin = blockIdx.x * 256 + threadIdx.x;  // [0, 524288)
  int w = lin & 63, h2 = (lin >> 6) & 63, o = (lin >> 12) & 63, b = lin >> 18;
  float v = tmp[((size_t)(b * 64 + h2) * 64 + o) * 64 + w];
  float kk = g[o] / sqrtf(fv[o] + 1e-5f);
  float r = (v - fm[o]) * kk + bb[o];
  out[lin] = (r > 0.0f) ? r : 0.0f;
}

extern "C" void kernel_launch(void* const* d_in, const int* in_sizes, int n_in,
                              void* d_out, int out_size, void* d_ws, size_t ws_size,
                              hipStream_t stream) {
  const float* x = (const float*)d_in[0];
  const float* base_w[3]   = {(const float*)d_in[1],  (const float*)d_in[7],  (const float*)d_in[13]};
  const float* spline_w[3] = {(const float*)d_in[2],  (const float*)d_in[8],  (const float*)d_in[14]};
  const float* bn_g[3]     = {(const float*)d_in[3],  (const float*)d_in[9],  (const float*)d_in[15]};
  const float* bn_b[3]     = {(const float*)d_in[4],  (const float*)d_in[10], (const float*)d_in[16]};
  const float* se_w1[3]    = {(const float*)d_in[5],  (const float*)d_in[11], (const float*)d_in[17]};
  const float* se_w2[3]    = {(const float*)d_in[6],  (const float*)d_in[12], (const float*)d_in[18]};
  const float* gp_conv_w = (const float*)d_in[19];
  const float* gp_conv_b = (const float*)d_in[20];
  const float* gp_bn_g   = (const float*)d_in[21];
  const float* gp_bn_b   = (const float*)d_in[22];
  const float* gp_se_w1  = (const float*)d_in[23];
  const float* gp_se_w2  = (const float*)d_in[24];
  const float* fuse_w    = (const float*)d_in[25];
  const float* fuse_b    = (const float*)d_in[26];
  const float* fuse_bn_g = (const float*)d_in[27];
  const float* fuse_bn_b = (const float*)d_in[28];
  float* out = (float*)d_out;

  char* wsp = (char*)d_ws;
  auto alloc = [&](size_t bytes) -> char* {
    char* p = wsp;
    wsp += (bytes + 255) & ~(size_t)255;
    return p;
  };
  // F[b][h][wp][ic] bf16, w-padded by DD each side
  __hip_bfloat16* F0 = (__hip_bfloat16*)alloc((size_t)2 * 64 * 76 * 448 * 2);    // 8.7 MB
  __hip_bfloat16* F1 = (__hip_bfloat16*)alloc((size_t)2 * 64 * 88 * 640 * 2);    // 14.4 MB
  __hip_bfloat16* F2 = (__hip_bfloat16*)alloc((size_t)2 * 64 * 100 * 832 * 2);   // 21.3 MB
  __hip_bfloat16* W0 = (__hip_bfloat16*)alloc((size_t)9 * 64 * 448 * 2);
  __hip_bfloat16* W1 = (__hip_bfloat16*)alloc((size_t)9 * 64 * 640 * 2);
  __hip_bfloat16* W2 = (__hip_bfloat16*)alloc((size_t)9 * 64 * 832 * 2);
  float* C0r  = (float*)alloc((size_t)3 * 3 * 64 * 4);
  float* ypart = (float*)alloc((size_t)3 * SLAB * 4);                            // 18.9 MB
  float* y    = ypart;               // reduced in-place into slab 0
  float* tmp  = ypart + SLAB;        // slab 1 dead after bnstats_k -> reuse
  float* bnm = (float*)alloc(192 * 4);
  float* bnv = (float*)alloc(192 * 4);
  float* se_mean = (float*)alloc(384 * 4);
  float* A1  = (float*)alloc(384 * 4);
  float* A0  = (float*)alloc(384 * 4);
  float* xm  = (float*)alloc(128 * 4);
  float* fgp = (float*)alloc(128 * 4);
  float* fwT = (float*)alloc((size_t)12288 * 4);
  float* fm  = (float*)alloc(64 * 4);
  float* fv  = (float*)alloc(64 * 4);

  features_k<3, 6><<<2432, 256, 0, stream>>>(x, F0);     // 2*64*64*76 /256
  features_k<6, 12><<<2816, 256, 0, stream>>>(x, F1);    // 2*64*64*88 /256
  features_k<9, 18><<<3200, 256, 0, stream>>>(x, F2);    // 2*64*64*100/256

  wprep_k<7><<<1008, 256, 0, stream>>>(base_w[0], spline_w[0], W0);
  wprep_k<10><<<1440, 256, 0, stream>>>(base_w[1], spline_w[1], W1);
  wprep_k<13><<<1872, 256, 0, stream>>>(base_w[2], spline_w[2], W2);

  c0r_k<3><<<3, 64, 0, stream>>>(W0, C0r, 0);
  c0r_k<6><<<3, 64, 0, stream>>>(W1, C0r, 192);
  c0r_k<9><<<3, 64, 0, stream>>>(W2, C0r, 384);

  xmean_k<<<128, 256, 0, stream>>>(x, xm);

  conv_all_k<<<576, 128, 0, stream>>>(
      (const short*)F0, (const short*)F1, (const short*)F2,
      (const short*)W0, (const short*)W1, (const short*)W2, C0r, ypart);

  bnstats_k<<<192, 256, 0, stream>>>(ypart, bnm, bnv);
  sesum_k<<<384, 256, 0, stream>>>(y, bnm, bnv, bn_g[0], bn_b[0], bn_g[1], bn_b[1],
                                   bn_g[2], bn_b[2], se_mean);
  semlp_k<<<6, 64, 0, stream>>>(se_mean, bnm, bnv, bn_g[0], bn_b[0], bn_g[1], bn_b[1],
                                bn_g[2], bn_b[2], se_w1[0], se_w1[1], se_w1[2],
                                se_w2[0], se_w2[1], se_w2[2], A1, A0);
  gp_k<<<1, 128, 0, stream>>>(xm, gp_conv_w, gp_conv_b, gp_bn_g, gp_bn_b, gp_se_w1,
                              gp_se_w2, fuse_w, fgp);
  fusewt_k<<<48, 256, 0, stream>>>(fuse_w, fwT);
  fuse_k<<<128, 256, 0, stream>>>(y, A1, A0, fwT, fuse_b, fgp, tmp);
  fstats_k<<<64, 256, 0, stream>>>(tmp, fm, fv);
  final_k<<<2048, 256, 0, stream>>>(tmp, fm, fv, fuse_bn_g, fuse_bn_b, out);
}

// Round 3
// 333.947 us; speedup vs baseline: 2.5133x; 1.4046x over previous
//
#include <hip/hip_runtime.h>
#include <hip/hip_bf16.h>
#include <math.h>

#define DEV __device__ __forceinline__

static constexpr int HW  = 4096;    // H*W
static constexpr int POS = 8192;    // B*H*W
static constexpr int SLAB = 6 * 64 * 4096;  // one ksplit partial slab (floats)

typedef __attribute__((ext_vector_type(8)))  short short8;
typedef __attribute__((ext_vector_type(16))) float floatx16;

// ---------- B-spline basis (order 3), mirrors reference Cox-de Boor ----------
template<int G>
DEV void bsplines(float x, float* out /* G+3 values */) {
  const float h = 2.0f / (float)G;
  float knot[G + 7];
#pragma unroll
  for (int t = 0; t < G + 7; ++t) knot[t] = -1.0f + (float)(t - 3) * h;
  float bb[G + 6];
#pragma unroll
  for (int t = 0; t < G + 6; ++t) bb[t] = (x >= knot[t] && x < knot[t + 1]) ? 1.0f : 0.0f;
#pragma unroll
  for (int j = 1; j <= 3; ++j) {
#pragma unroll
    for (int t = 0; t < G + 6 - j; ++t) {
      float left  = (x - knot[t]) / (knot[t + j] - knot[t]);
      float right = (knot[t + j + 1] - x) / (knot[t + j + 1] - knot[t + 1]);
      bb[t] = left * bb[t] + right * bb[t + 1];
    }
  }
#pragma unroll
  for (int t = 0; t < G + 3; ++t) out[t] = bb[t];
}

DEV float sigmoidf_(float x) { return 1.0f / (1.0f + __expf(-x)); }

DEV float block_reduce_256(float v, float* sb) {  // blockDim.x == 256
  __syncthreads();
#pragma unroll
  for (int off = 32; off > 0; off >>= 1) v += __shfl_down(v, off, 64);
  int lane = threadIdx.x & 63, wid = threadIdx.x >> 6;
  if (lane == 0) sb[wid] = v;
  __syncthreads();
  return sb[0] + sb[1] + sb[2] + sb[3];
}

// ================= prep kernel bodies =================

// weight repack: Wt[tap][o][ic] bf16, ic = i*CF + c
template<int CF>
DEV void wprep_body(const float* __restrict__ base_w, const float* __restrict__ spline_w,
                    __hip_bfloat16* __restrict__ Wt, int bid) {
  constexpr int KC = 64 * CF;
  int lin = bid * 256 + threadIdx.x;  // (tap, o, ic), 9*64*KC exact
  int ic = lin % KC;
  int rest = lin / KC;
  int o = rest & 63, tap = rest >> 6;
  int c = ic % CF, i = ic / CF;
  float v = (c == 0) ? base_w[(o * 64 + i) * 9 + tap]
                     : spline_w[((o * 64 + i) * 9 + tap) * (CF - 1) + (c - 1)];
  Wt[lin] = __float2bfloat16(v);
}

// C0r[br][ki][o] from fp32 spline_w directly (no dependency on Wt)
template<int G>
DEV void c0r_body(int ki, const float* __restrict__ sw, float* __restrict__ out,
                  float* shmem /* >=256 floats */) {
  constexpr int NB = G + 3;
  int o = threadIdx.x & 63, part = threadIdx.x >> 6;  // 4 parts over i
  float b0[NB];
  bsplines<G>(0.0f, b0);
  float s = 0.0f;
  for (int kj = 0; kj < 3; ++kj) {
    int tap = ki * 3 + kj;
    for (int i = part * 16; i < part * 16 + 16; ++i) {
      const float* p = sw + ((size_t)(o * 64 + i) * 9 + tap) * NB;
#pragma unroll
      for (int c = 0; c < NB; ++c) s += p[c] * b0[c];
    }
  }
  shmem[part * 64 + o] = s;
  __syncthreads();
  if (part == 0)
    out[ki * 64 + o] = shmem[o] + shmem[64 + o] + shmem[128 + o] + shmem[192 + o];
}

__global__ void prep_k(const float* bw0, const float* sw0, const float* bw1, const float* sw1,
                       const float* bw2, const float* sw2,
                       __hip_bfloat16* W0, __hip_bfloat16* W1, __hip_bfloat16* W2,
                       float* C0r, const float* fuse_w, float* fwT,
                       const float* x, float* xm, float* fstat) {
  __shared__ float shmem[256];
  int bid = blockIdx.x, tid = threadIdx.x;
  if (bid < 1008)      { wprep_body<7>(bw0, sw0, W0, bid); }
  else if (bid < 2448) { wprep_body<10>(bw1, sw1, W1, bid - 1008); }
  else if (bid < 4320) { wprep_body<13>(bw2, sw2, W2, bid - 2448); }
  else if (bid < 4329) {
    int idx = bid - 4320, br = idx / 3, ki = idx % 3;
    if (br == 0)      c0r_body<3>(ki, sw0, C0r, shmem);
    else if (br == 1) c0r_body<6>(ki, sw1, C0r + 192, shmem);
    else              c0r_body<9>(ki, sw2, C0r + 384, shmem);
  } else if (bid < 4377) {  // fuse_w transpose (branch part)
    int lin = (bid - 4329) * 256 + tid;  // [0, 12288)
    int o = lin & 63, i2 = lin >> 6;
    fwT[i2 * 64 + o] = fuse_w[o * 256 + i2];
  } else if (bid < 4505) {  // x mean per (b,i)
    int bi = bid - 4377;
    const float* p = x + (size_t)bi * HW;
    float s = 0.0f;
    for (int t = tid; t < HW; t += 256) s += p[t];
    s = block_reduce_256(s, shmem);
    if (tid == 0) xm[bi] = s * (1.0f / HW);
  } else {  // zero fuse-BN stat accumulators
    if (tid < 128) fstat[tid] = 0.0f;
  }
}

// ================= features: F[b][h][wp][ic], ic = i*CF + c =================
template<int G, int D>
DEV void features_body(const float* __restrict__ x, __hip_bfloat16* __restrict__ F, int bid) {
  constexpr int CF = G + 4;
  constexpr int NB = G + 3;
  constexpr int WP = 64 + 2 * D;
  constexpr int KC = 64 * CF;
  int lin = bid * 256 + threadIdx.x;  // (b,i,h,wp), wp innermost: 2*64*64*WP exact
  int wp = lin % WP;
  int rest = lin / WP;
  int h = rest & 63, i = (rest >> 6) & 63, b = rest >> 12;
  int w = wp - D;
  float xv = (w >= 0 && w < 64) ? x[((size_t)(b * 64 + i) * 64 + h) * 64 + w] : 0.0f;
  float s = xv * sigmoidf_(xv);
  float bas[NB];
  bsplines<G>(xv, bas);
  __hip_bfloat16* Fp = F + ((size_t)((b * 64 + h) * WP + wp)) * KC + i * CF;
  Fp[0] = __float2bfloat16(s);
#pragma unroll
  for (int c = 1; c < CF; ++c) Fp[c] = __float2bfloat16(bas[c - 1]);
}

__global__ void features_all_k(const float* __restrict__ x, __hip_bfloat16* F0,
                               __hip_bfloat16* F1, __hip_bfloat16* F2) {
  int bid = blockIdx.x;
  if (bid < 2432)      features_body<3, 6>(x, F0, bid);
  else if (bid < 5248) features_body<6, 12>(x, F1, bid - 2432);
  else                 features_body<9, 18>(x, F2, bid - 5248);
}

// ================= KAN conv: MFMA row-GEMM, software-pipelined =================
template<int CF, int DD>
DEV void conv_row(const short* __restrict__ rowF, const short* __restrict__ Wki,
                  floatx16 acc[2][2], int lr, int lq) {
  constexpr int KC = 64 * CF;
  constexpr int NG = 6 * CF;  // groups of 32 K-elems across 3 kj taps; always even
  short8 A0[2][2], A1[2][2], B0[2][2], B1[2][2];
  const short* wbase = Wki + lr * KC + lq * 8;
  const short* fbase = rowF + lr * KC + lq * 8;
  int kjn = 0, rn = 0;
#define LOADG(S) do { \
    const short* wp_ = wbase + kjn * (64 * KC) + rn * 32; \
    const short* fp_ = fbase + kjn * (DD * KC) + rn * 32; \
    A0[S][0] = *(const short8*)(wp_);           A0[S][1] = *(const short8*)(wp_ + 16); \
    A1[S][0] = *(const short8*)(wp_ + 32 * KC); A1[S][1] = *(const short8*)(wp_ + 32 * KC + 16); \
    B0[S][0] = *(const short8*)(fp_);           B0[S][1] = *(const short8*)(fp_ + 16); \
    B1[S][0] = *(const short8*)(fp_ + 32 * KC); B1[S][1] = *(const short8*)(fp_ + 32 * KC + 16); \
    if (++rn == 2 * CF) { rn = 0; ++kjn; } \
  } while (0)
#define MFMAG(S) do { \
    _Pragma("unroll") \
    for (int t = 0; t < 2; ++t) { \
      acc[0][0] = __builtin_amdgcn_mfma_f32_32x32x16_bf16(A0[S][t], B0[S][t], acc[0][0], 0, 0, 0); \
      acc[0][1] = __builtin_amdgcn_mfma_f32_32x32x16_bf16(A0[S][t], B1[S][t], acc[0][1], 0, 0, 0); \
      acc[1][0] = __builtin_amdgcn_mfma_f32_32x32x16_bf16(A1[S][t], B0[S][t], acc[1][0], 0, 0, 0); \
      acc[1][1] = __builtin_amdgcn_mfma_f32_32x32x16_bf16(A1[S][t], B1[S][t], acc[1][1], 0, 0, 0); \
    } \
  } while (0)
  LOADG(0);
#pragma unroll 1
  for (int g = 0; g < NG; g += 2) {
    LOADG(1);                  // group g+1 in flight while MFMA on g
    MFMAG(0);
    if (g + 2 < NG) LOADG(0);  // group g+2 in flight while MFMA on g+1
    MFMAG(1);
  }
#undef LOADG
#undef MFMAG
}

// block = (br, hts, b, ki) with ki FASTEST: the 3 ki-siblings read the SAME
// F source rows hs = hts*2 + wv -> F fetched from HBM ~once.
template<int CF, int DD>
DEV void conv_dev(int bid, const short* __restrict__ F, const short* __restrict__ W,
                  const float* __restrict__ C0r, float* __restrict__ ypart, int br) {
  constexpr int KC = 64 * CF;
  constexpr int WP = 64 + 2 * DD;
  int ki = bid % 3;
  int rest = bid / 3;
  int b = rest & 1;
  int hts = rest >> 1;           // [0,32) source h-pair
  int wv = threadIdx.x >> 6;
  int lane = threadIdx.x & 63;
  int lr = lane & 31, lq = lane >> 5;
  int hs = hts * 2 + wv;          // source row
  int h_out = hs - (ki - 1) * DD; // output row this source feeds for this ki
  bool valid = (h_out >= 0 && h_out < 64);
  int h_tgt = valid ? h_out : (h_out < 0 ? h_out + 64 : h_out - 64);  // mirror: C0 rows
  float* yb = ypart + (size_t)ki * SLAB + ((size_t)((br * 2 + b) * 64 + h_tgt)) * 4096;

  if (!valid) {  // this (hs,ki) pairs with an OOB-source output row: write C0 const
    const float* c0 = C0r + (br * 3 + ki) * 64;
#pragma unroll
    for (int wh = 0; wh < 2; ++wh) {
      int w = wh * 32 + lr;
#pragma unroll
      for (int ot = 0; ot < 2; ++ot)
#pragma unroll
        for (int reg = 0; reg < 16; ++reg) {
          int o = (reg & 3) + 8 * (reg >> 2) + 4 * lq + 32 * ot;
          yb[(size_t)o * 64 + w] = c0[o];
        }
    }
    return;
  }

  floatx16 acc[2][2];
#pragma unroll
  for (int ot = 0; ot < 2; ++ot)
#pragma unroll
    for (int wh = 0; wh < 2; ++wh)
#pragma unroll
      for (int r = 0; r < 16; ++r) acc[ot][wh][r] = 0.0f;

  const short* rowF = F + (size_t)(b * 64 + hs) * WP * KC;
  const short* Wki  = W + (size_t)(ki * 3) * 64 * KC;
  conv_row<CF, DD>(rowF, Wki, acc, lr, lq);

#pragma unroll
  for (int ot = 0; ot < 2; ++ot)
#pragma unroll
    for (int wh = 0; wh < 2; ++wh) {
      int w = wh * 32 + lr;
#pragma unroll
      for (int reg = 0; reg < 16; ++reg) {
        int o = (reg & 3) + 8 * (reg >> 2) + 4 * lq + 32 * ot;
        yb[(size_t)o * 64 + w] = acc[ot][wh][reg];
      }
    }
}

__global__ __launch_bounds__(128) void conv_all_k(
    const short* __restrict__ F0, const short* __restrict__ F1, const short* __restrict__ F2,
    const short* __restrict__ W0, const short* __restrict__ W1, const short* __restrict__ W2,
    const float* __restrict__ C0r, float* __restrict__ ypart) {
  int br = blockIdx.x / 192;
  int bid = blockIdx.x % 192;
  if (br == 0)      conv_dev<7, 6>(bid, F0, W0, C0r, ypart, 0);
  else if (br == 1) conv_dev<10, 12>(bid, F1, W1, C0r, ypart, 1);
  else              conv_dev<13, 18>(bid, F2, W2, C0r, ypart, 2);
}

// ============ fused: reduce k-split slabs + BN stats + SE pre-mean ============
__global__ void bnsesum_k(float* __restrict__ yp, float* __restrict__ bnm,
                          float* __restrict__ bnv,
                          const float* g0, const float* b0p, const float* g1, const float* b1p,
                          const float* g2, const float* b2p, float* __restrict__ se_mean) {
  int br = blockIdx.x >> 6, o = blockIdx.x & 63;
  __shared__ float sb[4];
  float s = 0.0f, q = 0.0f;
  for (int idx = threadIdx.x; idx < POS; idx += 256) {
    int b = idx >> 12, rem = idx & 4095;
    int h = rem >> 6, w = rem & 63;
    size_t base = ((size_t)((br * 2 + b) * 64 + h)) * 4096 + o * 64 + w;
    float v = yp[base] + yp[base + SLAB] + yp[base + 2 * (size_t)SLAB];
    yp[base] = v;
    s += v; q += v * v;
  }
  s = block_reduce_256(s, sb);
  q = block_reduce_256(q, sb);
  float m = s * (1.0f / POS);
  float var = q * (1.0f / POS) - m * m;
  if (threadIdx.x == 0) { bnm[br * 64 + o] = m; bnv[br * 64 + o] = var; }
  const float* gptr = (br == 0) ? g0 : ((br == 1) ? g1 : g2);
  const float* bptr = (br == 0) ? b0p : ((br == 1) ? b1p : b2p);
  float kk = gptr[o] / sqrtf(var + 1e-5f);
  float cc = bptr[o] - m * kk;
  float s0 = 0.0f, s1 = 0.0f;
  for (int idx = threadIdx.x; idx < POS; idx += 256) {  // L2-hot second pass
    int b = idx >> 12, rem = idx & 4095;
    int h = rem >> 6, w = rem & 63;
    float a = yp[((size_t)((br * 2 + b) * 64 + h)) * 4096 + o * 64 + w] * kk + cc;
    a = (a > 0.0f) ? a : 0.0f;
    if (b == 0) s0 += a; else s1 += a;
  }
  s0 = block_reduce_256(s0, sb);
  s1 = block_reduce_256(s1, sb);
  if (threadIdx.x == 0) {
    se_mean[(br * 2 + 0) * 64 + o] = s0 * (1.0f / HW);
    se_mean[(br * 2 + 1) * 64 + o] = s1 * (1.0f / HW);
  }
}

// ============ SE MLP fold (blocks 0-5) + global-pool branch (block 6) ============
__global__ void semlp_gp_k(const float* __restrict__ se_mean,
                           const float* __restrict__ bnm, const float* __restrict__ bnv,
                           const float* g0, const float* b0p, const float* g1, const float* b1p,
                           const float* g2, const float* b2p,
                           const float* w10, const float* w11, const float* w12,
                           const float* w20, const float* w21, const float* w22,
                           float* __restrict__ A1, float* __restrict__ A0,
                           const float* __restrict__ xm, const float* __restrict__ gw,
                           const float* __restrict__ gb, const float* __restrict__ bng,
                           const float* __restrict__ bnb, const float* __restrict__ gpw1,
                           const float* __restrict__ gpw2, const float* __restrict__ fuse_w,
                           float* __restrict__ fuse_gp) {
  __shared__ float sm[64];
  __shared__ float g0s[2][64], gp1s[2][64], gpvs[2][64];
  int tid = threadIdx.x;
  if (blockIdx.x < 6) {
    int bb = blockIdx.x, br = bb >> 1;
    const float* w1 = (br == 0) ? w10 : ((br == 1) ? w11 : w12);
    const float* w2 = (br == 0) ? w20 : ((br == 1) ? w21 : w22);
    const float* gptr = (br == 0) ? g0 : ((br == 1) ? g1 : g2);
    const float* bptr = (br == 0) ? b0p : ((br == 1) ? b1p : b2p);
    if (tid < 64) sm[tid] = se_mean[bb * 64 + tid];
    __syncthreads();
    if (tid < 64) {
      int o = tid;
      float z[4];
#pragma unroll
      for (int j = 0; j < 4; ++j) {
        float s = 0.0f;
        for (int c2 = 0; c2 < 64; ++c2) s += sm[c2] * w1[j * 64 + c2];
        z[j] = (s > 0.0f) ? s : 0.0f;
      }
      float t = 0.0f;
#pragma unroll
      for (int j = 0; j < 4; ++j) t += z[j] * w2[o * 4 + j];
      t = sigmoidf_(t);
      float m = bnm[br * 64 + o], var = bnv[br * 64 + o];
      float kk = gptr[o] / sqrtf(var + 1e-5f);
      float cc = bptr[o] - m * kk;
      A1[bb * 64 + o] = kk * t;  // relu(x)*t == relu(x*t), t>0
      A0[bb * 64 + o] = cc * t;
    }
  } else {  // global-pool branch, fully folded into fuse_gp[b][o]
    int b = tid >> 6, o = tid & 63;
    float gv = gb[o];
    for (int i = 0; i < 64; ++i) gv += xm[b * 64 + i] * gw[o * 64 + i];
    g0s[b][o] = gv;
    __syncthreads();
    float mu = 0.5f * (g0s[0][o] + g0s[1][o]);
    float df = g0s[0][o] - g0s[1][o];
    float var = 0.25f * df * df;
    float v = (gv - mu) / sqrtf(var + 1e-5f) * bng[o] + bnb[o];
    v = (v > 0.0f) ? v : 0.0f;
    gp1s[b][o] = v;
    __syncthreads();
    float z[4];
#pragma unroll
    for (int j = 0; j < 4; ++j) {
      float s = 0.0f;
      for (int c2 = 0; c2 < 64; ++c2) s += gp1s[b][c2] * gpw1[j * 64 + c2];
      z[j] = (s > 0.0f) ? s : 0.0f;
    }
    float t = 0.0f;
#pragma unroll
    for (int j = 0; j < 4; ++j) t += z[j] * gpw2[o * 4 + j];
    t = sigmoidf_(t);
    gpvs[b][o] = v * t;
    __syncthreads();
    float fg = 0.0f;
    for (int c2 = 0; c2 < 64; ++c2) fg += fuse_w[o * 256 + 192 + c2] * gpvs[b][c2];
    fuse_gp[b * 64 + o] = fg;
  }
}

// ============ fuse GEMM + atomic BN-stat partials (replaces fstats) ============
__global__ __launch_bounds__(256) void fuse_k(
    const float* __restrict__ y, const float* __restrict__ A1, const float* __restrict__ A0,
    const float* __restrict__ fwT, const float* __restrict__ fb, const float* __restrict__ fgp,
    float* __restrict__ tmp, float* __restrict__ fstat) {
  int bid = blockIdx.x;  // [0,128): b*64+h
  int b = bid >> 6, h = bid & 63;
  int tid = threadIdx.x;
  int wg = tid & 15, og = tid >> 4;
  int w0 = wg * 4, o0 = og * 4;
  float acc[4][4] = {};
  __shared__ float As[64][64];
  __shared__ float Ws[64][64];
  for (int br = 0; br < 3; ++br) {
#pragma unroll
    for (int m = 0; m < 16; ++m) {
      int lin = tid + m * 256;
      int oc = lin >> 6, wl = lin & 63;
      float v = y[(size_t)(br * 2 + b) * 262144 + (size_t)h * 4096 + oc * 64 + wl];
      float a1 = A1[(br * 2 + b) * 64 + oc], a0 = A0[(br * 2 + b) * 64 + oc];
      v = v * a1 + a0;
      As[oc][wl] = (v > 0.0f) ? v : 0.0f;
      Ws[oc][wl] = fwT[(br * 64 + oc) * 64 + wl];
    }
    __syncthreads();
#pragma unroll 8
    for (int ict = 0; ict < 64; ++ict) {
      float4 a  = *reinterpret_cast<const float4*>(&As[ict][w0]);
      float4 wv = *reinterpret_cast<const float4*>(&Ws[ict][o0]);
      acc[0][0] += a.x * wv.x; acc[0][1] += a.x * wv.y; acc[0][2] += a.x * wv.z; acc[0][3] += a.x * wv.w;
      acc[1][0] += a.y * wv.x; acc[1][1] += a.y * wv.y; acc[1][2] += a.y * wv.z; acc[1][3] += a.y * wv.w;
      acc[2][0] += a.z * wv.x; acc[2][1] += a.z * wv.y; acc[2][2] += a.z * wv.z; acc[2][3] += a.z * wv.w;
      acc[3][0] += a.w * wv.x; acc[3][1] += a.w * wv.y; acc[3][2] += a.w * wv.z; acc[3][3] += a.w * wv.w;
    }
    __syncthreads();
  }
  float* tp = tmp + (size_t)(b * 64 + h) * 4096;
#pragma unroll
  for (int j = 0; j < 4; ++j) {
    float bias = fb[o0 + j] + fgp[b * 64 + o0 + j];
    float4 v = make_float4(acc[0][j] + bias, acc[1][j] + bias, acc[2][j] + bias, acc[3][j] + bias);
    *reinterpret_cast<float4*>(&tp[(o0 + j) * 64 + w0]) = v;
    As[wg][o0 + j] = v.x + v.y + v.z + v.w;                           // per-o partial sum
    Ws[wg][o0 + j] = v.x * v.x + v.y * v.y + v.z * v.z + v.w * v.w;   // per-o partial sumsq
  }
  __syncthreads();
  if (tid < 64) {
    float s = 0.0f, q = 0.0f;
#pragma unroll
    for (int r = 0; r < 16; ++r) { s += As[r][tid]; q += Ws[r][tid]; }
    atomicAdd(&fstat[tid], s);
    atomicAdd(&fstat[64 + tid], q);
  }
}

// ---------- final BN+relu, write (B,Co,H,W) ----------
__global__ void final_k(const float* __restrict__ tmp, const float* __restrict__ fstat,
                        const float* __restrict__ g, const float* __restrict__ bb,
                        float* __restrict__ out) {
  int lin = blockIdx.x * 256 + threadIdx.x;  // [0, 524288)
  int w = lin & 63, h2 = (lin >> 6) & 63, o = (lin >> 12) & 63, b = lin >> 18;
  float v = tmp[((size_t)(b * 64 + h2) * 64 + o) * 64 + w];
  float m = fstat[o] * (1.0f / POS);
  float var = fstat[64 + o] * (1.0f / POS) - m * m;
  float kk = g[o] / sqrtf(var + 1e-5f);
  float r = (v - m) * kk + bb[o];
  out[lin] = (r > 0.0f) ? r : 0.0f;
}

extern "C" void kernel_launch(void* const* d_in, const int* in_sizes, int n_in,
                              void* d_out, int out_size, void* d_ws, size_t ws_size,
                              hipStream_t stream) {
  const float* x = (const float*)d_in[0];
  const float* base_w[3]   = {(const float*)d_in[1],  (const float*)d_in[7],  (const float*)d_in[13]};
  const float* spline_w[3] = {(const float*)d_in[2],  (const float*)d_in[8],  (const float*)d_in[14]};
  const float* bn_g[3]     = {(const float*)d_in[3],  (const float*)d_in[9],  (const float*)d_in[15]};
  const float* bn_b[3]     = {(const float*)d_in[4],  (const float*)d_in[10], (const float*)d_in[16]};
  const float* se_w1[3]    = {(const float*)d_in[5],  (const float*)d_in[11], (const float*)d_in[17]};
  const float* se_w2[3]    = {(const float*)d_in[6],  (const float*)d_in[12], (const float*)d_in[18]};
  const float* gp_conv_w = (const float*)d_in[19];
  const float* gp_conv_b = (const float*)d_in[20];
  const float* gp_bn_g   = (const float*)d_in[21];
  const float* gp_bn_b   = (const float*)d_in[22];
  const float* gp_se_w1  = (const float*)d_in[23];
  const float* gp_se_w2  = (const float*)d_in[24];
  const float* fuse_w    = (const float*)d_in[25];
  const float* fuse_b    = (const float*)d_in[26];
  const float* fuse_bn_g = (const float*)d_in[27];
  const float* fuse_bn_b = (const float*)d_in[28];
  float* out = (float*)d_out;

  char* wsp = (char*)d_ws;
  auto alloc = [&](size_t bytes) -> char* {
    char* p = wsp;
    wsp += (bytes + 255) & ~(size_t)255;
    return p;
  };
  __hip_bfloat16* F0 = (__hip_bfloat16*)alloc((size_t)2 * 64 * 76 * 448 * 2);
  __hip_bfloat16* F1 = (__hip_bfloat16*)alloc((size_t)2 * 64 * 88 * 640 * 2);
  __hip_bfloat16* F2 = (__hip_bfloat16*)alloc((size_t)2 * 64 * 100 * 832 * 2);
  __hip_bfloat16* W0 = (__hip_bfloat16*)alloc((size_t)9 * 64 * 448 * 2);
  __hip_bfloat16* W1 = (__hip_bfloat16*)alloc((size_t)9 * 64 * 640 * 2);
  __hip_bfloat16* W2 = (__hip_bfloat16*)alloc((size_t)9 * 64 * 832 * 2);
  float* C0r   = (float*)alloc((size_t)3 * 3 * 64 * 4);
  float* ypart = (float*)alloc((size_t)3 * SLAB * 4);
  float* y     = ypart;          // reduced in-place into slab 0
  float* tmp   = ypart + SLAB;   // slab 1 dead after bnsesum_k -> reuse
  float* bnm = (float*)alloc(192 * 4);
  float* bnv = (float*)alloc(192 * 4);
  float* se_mean = (float*)alloc(384 * 4);
  float* A1  = (float*)alloc(384 * 4);
  float* A0  = (float*)alloc(384 * 4);
  float* xm  = (float*)alloc(128 * 4);
  float* fgp = (float*)alloc(128 * 4);
  float* fwT = (float*)alloc((size_t)12288 * 4);
  float* fstat = (float*)alloc(128 * 4);

  prep_k<<<4506, 256, 0, stream>>>(base_w[0], spline_w[0], base_w[1], spline_w[1],
                                   base_w[2], spline_w[2], W0, W1, W2, C0r,
                                   fuse_w, fwT, x, xm, fstat);
  features_all_k<<<8448, 256, 0, stream>>>(x, F0, F1, F2);
  conv_all_k<<<576, 128, 0, stream>>>(
      (const short*)F0, (const short*)F1, (const short*)F2,
      (const short*)W0, (const short*)W1, (const short*)W2, C0r, ypart);
  bnsesum_k<<<192, 256, 0, stream>>>(ypart, bnm, bnv, bn_g[0], bn_b[0], bn_g[1], bn_b[1],
                                     bn_g[2], bn_b[2], se_mean);
  semlp_gp_k<<<7, 128, 0, stream>>>(se_mean, bnm, bnv, bn_g[0], bn_b[0], bn_g[1], bn_b[1],
                                    bn_g[2], bn_b[2], se_w1[0], se_w1[1], se_w1[2],
                                    se_w2[0], se_w2[1], se_w2[2], A1, A0,
                                    xm, gp_conv_w, gp_conv_b, gp_bn_g, gp_bn_b,
                                    gp_se_w1, gp_se_w2, fuse_w, fgp);
  fuse_k<<<128, 256, 0, stream>>>(y, A1, A0, fwT, fuse_b, fgp, tmp, fstat);
  final_k<<<2048, 256, 0, stream>>>(tmp, fstat, fuse_bn_g, fuse_bn_b, out);
}

// Round 4
// 324.337 us; speedup vs baseline: 2.5878x; 1.0296x over previous
//
#include <hip/hip_runtime.h>
#include <hip/hip_bf16.h>
#include <math.h>

#define DEV __device__ __forceinline__

static constexpr int HW  = 4096;    // H*W
static constexpr int POS = 8192;    // B*H*W
static constexpr int SLAB = 6 * 64 * 4096;  // one ksplit partial slab (floats)

typedef __attribute__((ext_vector_type(8)))  short short8;
typedef __attribute__((ext_vector_type(16))) float floatx16;

// ---------- B-spline basis (order 3), mirrors reference Cox-de Boor ----------
template<int G>
DEV void bsplines(float x, float* out /* G+3 values */) {
  const float h = 2.0f / (float)G;
  float knot[G + 7];
#pragma unroll
  for (int t = 0; t < G + 7; ++t) knot[t] = -1.0f + (float)(t - 3) * h;
  float bb[G + 6];
#pragma unroll
  for (int t = 0; t < G + 6; ++t) bb[t] = (x >= knot[t] && x < knot[t + 1]) ? 1.0f : 0.0f;
#pragma unroll
  for (int j = 1; j <= 3; ++j) {
#pragma unroll
    for (int t = 0; t < G + 6 - j; ++t) {
      float left  = (x - knot[t]) / (knot[t + j] - knot[t]);
      float right = (knot[t + j + 1] - x) / (knot[t + j + 1] - knot[t + 1]);
      bb[t] = left * bb[t] + right * bb[t + 1];
    }
  }
#pragma unroll
  for (int t = 0; t < G + 3; ++t) out[t] = bb[t];
}

DEV float sigmoidf_(float x) { return 1.0f / (1.0f + __expf(-x)); }

DEV float block_reduce_256(float v, float* sb) {  // blockDim.x == 256
  __syncthreads();
#pragma unroll
  for (int off = 32; off > 0; off >>= 1) v += __shfl_down(v, off, 64);
  int lane = threadIdx.x & 63, wid = threadIdx.x >> 6;
  if (lane == 0) sb[wid] = v;
  __syncthreads();
  return sb[0] + sb[1] + sb[2] + sb[3];
}

// ================= prep kernel bodies =================

// weight repack: Wt[tap][o][ic] bf16, ic = i*CF + c
template<int CF>
DEV void wprep_body(const float* __restrict__ base_w, const float* __restrict__ spline_w,
                    __hip_bfloat16* __restrict__ Wt, int bid) {
  constexpr int KC = 64 * CF;
  int lin = bid * 256 + threadIdx.x;  // (tap, o, ic), 9*64*KC exact
  int ic = lin % KC;
  int rest = lin / KC;
  int o = rest & 63, tap = rest >> 6;
  int c = ic % CF, i = ic / CF;
  float v = (c == 0) ? base_w[(o * 64 + i) * 9 + tap]
                     : spline_w[((o * 64 + i) * 9 + tap) * (CF - 1) + (c - 1)];
  Wt[lin] = __float2bfloat16(v);
}

// C0r[br][ki][o] from fp32 spline_w directly
template<int G>
DEV void c0r_body(int ki, const float* __restrict__ sw, float* __restrict__ out,
                  float* shmem /* >=256 floats */) {
  constexpr int NB = G + 3;
  int o = threadIdx.x & 63, part = threadIdx.x >> 6;  // 4 parts over i
  float b0[NB];
  bsplines<G>(0.0f, b0);
  float s = 0.0f;
  for (int kj = 0; kj < 3; ++kj) {
    int tap = ki * 3 + kj;
    for (int i = part * 16; i < part * 16 + 16; ++i) {
      const float* p = sw + ((size_t)(o * 64 + i) * 9 + tap) * NB;
#pragma unroll
      for (int c = 0; c < NB; ++c) s += p[c] * b0[c];
    }
  }
  shmem[part * 64 + o] = s;
  __syncthreads();
  if (part == 0)
    out[ki * 64 + o] = shmem[o] + shmem[64 + o] + shmem[128 + o] + shmem[192 + o];
}

__global__ void prep_k(const float* bw0, const float* sw0, const float* bw1, const float* sw1,
                       const float* bw2, const float* sw2,
                       __hip_bfloat16* W0, __hip_bfloat16* W1, __hip_bfloat16* W2,
                       float* C0r, const float* fuse_w, float* fwT,
                       const float* x, float* xm, float* accz /* 896 floats */) {
  __shared__ float shmem[256];
  int bid = blockIdx.x, tid = threadIdx.x;
  if (bid < 1008)      { wprep_body<7>(bw0, sw0, W0, bid); }
  else if (bid < 2448) { wprep_body<10>(bw1, sw1, W1, bid - 1008); }
  else if (bid < 4320) { wprep_body<13>(bw2, sw2, W2, bid - 2448); }
  else if (bid < 4329) {
    int idx = bid - 4320, br = idx / 3, ki = idx % 3;
    if (br == 0)      c0r_body<3>(ki, sw0, C0r, shmem);
    else if (br == 1) c0r_body<6>(ki, sw1, C0r + 192, shmem);
    else              c0r_body<9>(ki, sw2, C0r + 384, shmem);
  } else if (bid < 4377) {  // fuse_w transpose (branch part)
    int lin = (bid - 4329) * 256 + tid;  // [0, 12288)
    int o = lin & 63, i2 = lin >> 6;
    fwT[i2 * 64 + o] = fuse_w[o * 256 + i2];
  } else if (bid < 4505) {  // x mean per (b,i)
    int bi = bid - 4377;
    const float* p = x + (size_t)bi * HW;
    float s = 0.0f;
    for (int t = tid; t < HW; t += 256) s += p[t];
    s = block_reduce_256(s, shmem);
    if (tid == 0) xm[bi] = s * (1.0f / HW);
  } else {  // zero atomic accumulators: fstat[128] | bnacc_s[192] | bnacc_q[192] | se_acc[384]
    for (int t = tid; t < 896; t += 256) accz[t] = 0.0f;
  }
}

// ============ features: F[b][h][wp][ic], ic = i*CF + c; i as lane ============
// block 256 = 4 wp-sub x 64 i -> writes are 64*CF-contiguous bf16 bursts.
template<int G, int D>
DEV void features_body(const float* __restrict__ x, __hip_bfloat16* __restrict__ F, int bid) {
  constexpr int CF = G + 4;
  constexpr int NB = G + 3;
  constexpr int WP = 64 + 2 * D;
  constexpr int NG = WP / 4;          // 19 | 22 | 25, exact
  constexpr int KC = 64 * CF;
  int i = threadIdx.x & 63, ws = threadIdx.x >> 6;
  int wpg = bid % NG;
  int rest = bid / NG;
  int h = rest & 63, b = rest >> 6;
  int wp = wpg * 4 + ws;
  int w = wp - D;
  float xv = (w >= 0 && w < 64) ? x[((size_t)(b * 64 + i) * 64 + h) * 64 + w] : 0.0f;
  float s = xv * sigmoidf_(xv);
  float bas[NB];
  bsplines<G>(xv, bas);
  __hip_bfloat16* Fp = F + ((size_t)((b * 64 + h) * WP + wp)) * KC + i * CF;
  Fp[0] = __float2bfloat16(s);
#pragma unroll
  for (int c = 1; c < CF; ++c) Fp[c] = __float2bfloat16(bas[c - 1]);
}

__global__ void features_all_k(const float* __restrict__ x, __hip_bfloat16* F0,
                               __hip_bfloat16* F1, __hip_bfloat16* F2) {
  int bid = blockIdx.x;
  if (bid < 2432)      features_body<3, 6>(x, F0, bid);
  else if (bid < 5248) features_body<6, 12>(x, F1, bid - 2432);
  else                 features_body<9, 18>(x, F2, bid - 5248);
}

// ================= KAN conv: MFMA row-GEMM, static unrolled K =================
DEV floatx16 mfma_bf16(short8 a, short8 b, floatx16 c) {
  return __builtin_amdgcn_mfma_f32_32x32x16_bf16(a, b, c, 0, 0, 0);
}

template<int CF, int DD>
DEV void conv_row(const short* __restrict__ rowF, const short* __restrict__ Wki,
                  floatx16 acc[2][2], int lr, int lq) {
  constexpr int KC = 64 * CF;
  const short* wb = Wki + lr * KC + lq * 8;
  const short* fb = rowF + lr * KC + lq * 8;
#pragma unroll
  for (int kj = 0; kj < 3; ++kj) {
    const short* w0p = wb + kj * (64 * KC);
    const short* f0p = fb + kj * (DD * KC);
#pragma unroll 4
    for (int s = 0; s < 4 * CF; ++s) {   // 16-K per step, all offsets affine
      short8 a0 = *(const short8*)(w0p + s * 16);
      short8 a1 = *(const short8*)(w0p + 32 * KC + s * 16);
      short8 b0 = *(const short8*)(f0p + s * 16);
      short8 b1 = *(const short8*)(f0p + 32 * KC + s * 16);
      acc[0][0] = mfma_bf16(a0, b0, acc[0][0]);
      acc[0][1] = mfma_bf16(a0, b1, acc[0][1]);
      acc[1][0] = mfma_bf16(a1, b0, acc[1][0]);
      acc[1][1] = mfma_bf16(a1, b1, acc[1][1]);
    }
  }
}

// Source-centric: block owns source rows hs = hp*2 + wv; ki-siblings (same hs)
// are swizzled onto the SAME XCD so F rows are L2-shared.
template<int CF, int DD>
DEV void conv_dev(int ki, int b, int hp, const short* __restrict__ F,
                  const short* __restrict__ W, const float* __restrict__ C0r,
                  float* __restrict__ ypart, int br) {
  constexpr int KC = 64 * CF;
  constexpr int WP = 64 + 2 * DD;
  int wv = threadIdx.x >> 6;
  int lane = threadIdx.x & 63;
  int lr = lane & 31, lq = lane >> 5;
  int hs = hp * 2 + wv;           // source row (always valid)
  int h_out = hs - (ki - 1) * DD; // output row this source feeds for this ki
  bool valid = (h_out >= 0 && h_out < 64);
  int h_tgt = valid ? h_out : (h_out < 0 ? h_out + 64 : h_out - 64);  // mirror: C0 rows
  float* yb = ypart + (size_t)ki * SLAB + ((size_t)((br * 2 + b) * 64 + h_tgt)) * 4096;

  if (!valid) {  // paired output row's source is OOB: constant C0 contribution
    const float* c0 = C0r + (br * 3 + ki) * 64;
#pragma unroll
    for (int wh = 0; wh < 2; ++wh) {
      int w = wh * 32 + lr;
#pragma unroll
      for (int ot = 0; ot < 2; ++ot)
#pragma unroll
        for (int reg = 0; reg < 16; ++reg) {
          int o = (reg & 3) + 8 * (reg >> 2) + 4 * lq + 32 * ot;
          yb[(size_t)o * 64 + w] = c0[o];
        }
    }
    return;
  }

  floatx16 acc[2][2];
#pragma unroll
  for (int ot = 0; ot < 2; ++ot)
#pragma unroll
    for (int wh = 0; wh < 2; ++wh)
#pragma unroll
      for (int r = 0; r < 16; ++r) acc[ot][wh][r] = 0.0f;

  const short* rowF = F + (size_t)(b * 64 + hs) * WP * KC;
  const short* Wki  = W + (size_t)(ki * 3) * 64 * KC;
  conv_row<CF, DD>(rowF, Wki, acc, lr, lq);

#pragma unroll
  for (int ot = 0; ot < 2; ++ot)
#pragma unroll
    for (int wh = 0; wh < 2; ++wh) {
      int w = wh * 32 + lr;
#pragma unroll
      for (int reg = 0; reg < 16; ++reg) {
        int o = (reg & 3) + 8 * (reg >> 2) + 4 * lq + 32 * ot;
        yb[(size_t)o * 64 + w] = acc[ot][wh][reg];
      }
    }
}

__global__ __launch_bounds__(128) void conv_all_k(
    const short* __restrict__ F0, const short* __restrict__ F1, const short* __restrict__ F2,
    const short* __restrict__ W0, const short* __restrict__ W1, const short* __restrict__ W2,
    const float* __restrict__ C0r, float* __restrict__ ypart) {
  // XCD swizzle: ki-siblings at bid, bid+8, bid+16 -> same XCD (bid % 8 fixed)
  int bid = blockIdx.x;                 // [0,576)
  int e  = bid & 7;
  int t  = bid >> 3;                    // [0,72)
  int ki = t % 3;
  int m  = (t / 3) * 8 + e;             // [0,192) combo (br,b,hp)
  int br = m >> 6, b = (m >> 5) & 1, hp = m & 31;
  if (br == 0)      conv_dev<7, 6>(ki, b, hp, F0, W0, C0r, ypart, 0);
  else if (br == 1) conv_dev<10, 12>(ki, b, hp, F1, W1, C0r, ypart, 1);
  else              conv_dev<13, 18>(ki, b, hp, F2, W2, C0r, ypart, 2);
}

// ====== reduce 3 k-split slabs into slab0 + atomic per-(br,o) BN partials ======
__global__ void rb_k(float* __restrict__ yp, float* __restrict__ bnacc_s,
                     float* __restrict__ bnacc_q) {
  int bid = blockIdx.x;                 // [0,1536) = bb(6) x chunk(256)
  int bb = bid / 256, chunk = bid % 256;
  int br = bb >> 1;
  int tid = threadIdx.x;
  size_t base = (size_t)bb * 262144 + chunk * 1024 + tid * 4;
  float4 v0 = *(const float4*)(yp + base);
  float4 v1 = *(const float4*)(yp + base + SLAB);
  float4 v2 = *(const float4*)(yp + base + 2 * (size_t)SLAB);
  float4 v = make_float4(v0.x + v1.x + v2.x, v0.y + v1.y + v2.y,
                         v0.z + v1.z + v2.z, v0.w + v1.w + v2.w);
  *(float4*)(yp + base) = v;
  float s = v.x + v.y + v.z + v.w;
  float q = v.x * v.x + v.y * v.y + v.z * v.z + v.w * v.w;
  s += __shfl_down(s, 8, 16); s += __shfl_down(s, 4, 16);
  s += __shfl_down(s, 2, 16); s += __shfl_down(s, 1, 16);
  q += __shfl_down(q, 8, 16); q += __shfl_down(q, 4, 16);
  q += __shfl_down(q, 2, 16); q += __shfl_down(q, 1, 16);
  if ((tid & 15) == 0) {
    int o = (chunk * 16 + (tid >> 4)) & 63;
    atomicAdd(&bnacc_s[br * 64 + o], s);
    atomicAdd(&bnacc_q[br * 64 + o], q);
  }
}

// ====== SE pre-sum: atomic sum over (h,w) of relu(bn(y)) per (bb,o) ======
__global__ void sesum_k(const float* __restrict__ y, const float* __restrict__ bnacc_s,
                        const float* __restrict__ bnacc_q,
                        const float* g0, const float* b0p, const float* g1, const float* b1p,
                        const float* g2, const float* b2p, float* __restrict__ se_acc) {
  int bid = blockIdx.x;                 // [0,384) = bb(6) x h(64)
  int bb = bid >> 6, h = bid & 63;
  int br = bb >> 1;
  int tid = threadIdx.x;
  int o = tid >> 2, wq = tid & 3;
  const float* gptr = (br == 0) ? g0 : ((br == 1) ? g1 : g2);
  const float* bptr = (br == 0) ? b0p : ((br == 1) ? b1p : b2p);
  float mu = bnacc_s[br * 64 + o] * (1.0f / POS);
  float var = bnacc_q[br * 64 + o] * (1.0f / POS) - mu * mu;
  float kk = gptr[o] / sqrtf(var + 1e-5f);
  float cc = bptr[o] - mu * kk;
  const float* row = y + (size_t)bb * 262144 + (size_t)h * 4096 + o * 64 + wq * 16;
  float s = 0.0f;
#pragma unroll
  for (int j = 0; j < 4; ++j) {
    float4 v = *(const float4*)(row + j * 4);
    float a;
    a = v.x * kk + cc; s += (a > 0.0f) ? a : 0.0f;
    a = v.y * kk + cc; s += (a > 0.0f) ? a : 0.0f;
    a = v.z * kk + cc; s += (a > 0.0f) ? a : 0.0f;
    a = v.w * kk + cc; s += (a > 0.0f) ? a : 0.0f;
  }
  s += __shfl_down(s, 2, 4);
  s += __shfl_down(s, 1, 4);
  if (wq == 0) atomicAdd(&se_acc[bb * 64 + o], s);
}

// ============ SE MLP fold (blocks 0-5) + global-pool branch (block 6) ============
__global__ void semlp_gp_k(const float* __restrict__ se_acc,
                           const float* __restrict__ bnacc_s, const float* __restrict__ bnacc_q,
                           const float* g0, const float* b0p, const float* g1, const float* b1p,
                           const float* g2, const float* b2p,
                           const float* w10, const float* w11, const float* w12,
                           const float* w20, const float* w21, const float* w22,
                           float* __restrict__ A1, float* __restrict__ A0,
                           const float* __restrict__ xm, const float* __restrict__ gw,
                           const float* __restrict__ gb, const float* __restrict__ bng,
                           const float* __restrict__ bnb, const float* __restrict__ gpw1,
                           const float* __restrict__ gpw2, const float* __restrict__ fuse_w,
                           float* __restrict__ fuse_gp) {
  __shared__ float sm[64];
  __shared__ float g0s[2][64], gp1s[2][64], gpvs[2][64];
  int tid = threadIdx.x;
  if (blockIdx.x < 6) {
    int bb = blockIdx.x, br = bb >> 1;
    const float* w1 = (br == 0) ? w10 : ((br == 1) ? w11 : w12);
    const float* w2 = (br == 0) ? w20 : ((br == 1) ? w21 : w22);
    const float* gptr = (br == 0) ? g0 : ((br == 1) ? g1 : g2);
    const float* bptr = (br == 0) ? b0p : ((br == 1) ? b1p : b2p);
    if (tid < 64) sm[tid] = se_acc[bb * 64 + tid] * (1.0f / HW);
    __syncthreads();
    if (tid < 64) {
      int o = tid;
      float z[4];
#pragma unroll
      for (int j = 0; j < 4; ++j) {
        float s = 0.0f;
        for (int c2 = 0; c2 < 64; ++c2) s += sm[c2] * w1[j * 64 + c2];
        z[j] = (s > 0.0f) ? s : 0.0f;
      }
      float t = 0.0f;
#pragma unroll
      for (int j = 0; j < 4; ++j) t += z[j] * w2[o * 4 + j];
      t = sigmoidf_(t);
      float mu = bnacc_s[br * 64 + o] * (1.0f / POS);
      float var = bnacc_q[br * 64 + o] * (1.0f / POS) - mu * mu;
      float kk = gptr[o] / sqrtf(var + 1e-5f);
      float cc = bptr[o] - mu * kk;
      A1[bb * 64 + o] = kk * t;  // relu(x)*t == relu(x*t), t>0
      A0[bb * 64 + o] = cc * t;
    }
  } else {  // global-pool branch, fully folded into fuse_gp[b][o]
    int b = tid >> 6, o = tid & 63;
    float gv = gb[o];
    for (int i = 0; i < 64; ++i) gv += xm[b * 64 + i] * gw[o * 64 + i];
    g0s[b][o] = gv;
    __syncthreads();
    float mu = 0.5f * (g0s[0][o] + g0s[1][o]);
    float df = g0s[0][o] - g0s[1][o];
    float var = 0.25f * df * df;
    float v = (gv - mu) / sqrtf(var + 1e-5f) * bng[o] + bnb[o];
    v = (v > 0.0f) ? v : 0.0f;
    gp1s[b][o] = v;
    __syncthreads();
    float z[4];
#pragma unroll
    for (int j = 0; j < 4; ++j) {
      float s = 0.0f;
      for (int c2 = 0; c2 < 64; ++c2) s += gp1s[b][c2] * gpw1[j * 64 + c2];
      z[j] = (s > 0.0f) ? s : 0.0f;
    }
    float t = 0.0f;
#pragma unroll
    for (int j = 0; j < 4; ++j) t += z[j] * gpw2[o * 4 + j];
    t = sigmoidf_(t);
    gpvs[b][o] = v * t;
    __syncthreads();
    float fg = 0.0f;
    for (int c2 = 0; c2 < 64; ++c2) fg += fuse_w[o * 256 + 192 + c2] * gpvs[b][c2];
    fuse_gp[b * 64 + o] = fg;
  }
}

// ============ fuse GEMM (w-split, 256 blocks) + atomic BN-stat partials ============
__global__ __launch_bounds__(256) void fuse_k(
    const float* __restrict__ y, const float* __restrict__ A1, const float* __restrict__ A0,
    const float* __restrict__ fwT, const float* __restrict__ fb, const float* __restrict__ fgp,
    float* __restrict__ tmp, float* __restrict__ fstat) {
  int bid = blockIdx.x;                 // [0,256): (b, h, w-half)
  int b = bid >> 7, h = (bid >> 1) & 63, wh = bid & 1;
  int tid = threadIdx.x;
  int wg = tid & 7, og = tid >> 3;      // 8 w-groups x 32 o-groups
  int w0 = wg * 4, o0 = og * 2;
  float acc[2][4] = {};
  __shared__ float As[64][32];
  __shared__ float Ws[64][64];
  for (int br = 0; br < 3; ++br) {
#pragma unroll
    for (int m = 0; m < 8; ++m) {       // stage As: 64 oc x 32 w
      int lin = tid + m * 256;
      int oc = lin >> 5, wl = lin & 31;
      float v = y[(size_t)(br * 2 + b) * 262144 + (size_t)h * 4096 + oc * 64 + wh * 32 + wl];
      float a1 = A1[(br * 2 + b) * 64 + oc], a0 = A0[(br * 2 + b) * 64 + oc];
      v = v * a1 + a0;
      As[oc][wl] = (v > 0.0f) ? v : 0.0f;
    }
#pragma unroll
    for (int m = 0; m < 16; ++m) {      // stage Ws: 64 oc x 64 o
      int lin = tid + m * 256;
      int oc = lin >> 6, ol = lin & 63;
      Ws[oc][ol] = fwT[(br * 64 + oc) * 64 + ol];
    }
    __syncthreads();
#pragma unroll 8
    for (int ict = 0; ict < 64; ++ict) {
      float4 a = *reinterpret_cast<const float4*>(&As[ict][w0]);
      float2 wv = *reinterpret_cast<const float2*>(&Ws[ict][o0]);
      acc[0][0] += wv.x * a.x; acc[0][1] += wv.x * a.y; acc[0][2] += wv.x * a.z; acc[0][3] += wv.x * a.w;
      acc[1][0] += wv.y * a.x; acc[1][1] += wv.y * a.y; acc[1][2] += wv.y * a.z; acc[1][3] += wv.y * a.w;
    }
    __syncthreads();
  }
  float* tp = tmp + (size_t)(b * 64 + h) * 4096 + wh * 32;
  float ps[2], pq[2];
#pragma unroll
  for (int oo = 0; oo < 2; ++oo) {
    int o = o0 + oo;
    float bias = fb[o] + fgp[b * 64 + o];
    float4 v = make_float4(acc[oo][0] + bias, acc[oo][1] + bias,
                           acc[oo][2] + bias, acc[oo][3] + bias);
    *reinterpret_cast<float4*>(&tp[o * 64 + w0]) = v;
    ps[oo] = v.x + v.y + v.z + v.w;
    pq[oo] = v.x * v.x + v.y * v.y + v.z * v.z + v.w * v.w;
  }
  __syncthreads();
#pragma unroll
  for (int oo = 0; oo < 2; ++oo) { As[o0 + oo][wg] = ps[oo]; Ws[o0 + oo][wg] = pq[oo]; }
  __syncthreads();
  if (tid < 64) {
    float s = 0.0f, q = 0.0f;
#pragma unroll
    for (int r = 0; r < 8; ++r) { s += As[tid][r]; q += Ws[tid][r]; }
    atomicAdd(&fstat[tid], s);
    atomicAdd(&fstat[64 + tid], q);
  }
}

// ---------- final BN+relu, write (B,Co,H,W) ----------
__global__ void final_k(const float* __restrict__ tmp, const float* __restrict__ fstat,
                        const float* __restrict__ g, const float* __restrict__ bb,
                        float* __restrict__ out) {
  int lin = blockIdx.x * 256 + threadIdx.x;  // [0, 524288)
  int w = lin & 63, h2 = (lin >> 6) & 63, o = (lin >> 12) & 63, b = lin >> 18;
  float v = tmp[((size_t)(b * 64 + h2) * 64 + o) * 64 + w];
  float m = fstat[o] * (1.0f / POS);
  float var = fstat[64 + o] * (1.0f / POS) - m * m;
  float kk = g[o] / sqrtf(var + 1e-5f);
  float r = (v - m) * kk + bb[o];
  out[lin] = (r > 0.0f) ? r : 0.0f;
}

extern "C" void kernel_launch(void* const* d_in, const int* in_sizes, int n_in,
                              void* d_out, int out_size, void* d_ws, size_t ws_size,
                              hipStream_t stream) {
  const float* x = (const float*)d_in[0];
  const float* base_w[3]   = {(const float*)d_in[1],  (const float*)d_in[7],  (const float*)d_in[13]};
  const float* spline_w[3] = {(const float*)d_in[2],  (const float*)d_in[8],  (const float*)d_in[14]};
  const float* bn_g[3]     = {(const float*)d_in[3],  (const float*)d_in[9],  (const float*)d_in[15]};
  const float* bn_b[3]     = {(const float*)d_in[4],  (const float*)d_in[10], (const float*)d_in[16]};
  const float* se_w1[3]    = {(const float*)d_in[5],  (const float*)d_in[11], (const float*)d_in[17]};
  const float* se_w2[3]    = {(const float*)d_in[6],  (const float*)d_in[12], (const float*)d_in[18]};
  const float* gp_conv_w = (const float*)d_in[19];
  const float* gp_conv_b = (const float*)d_in[20];
  const float* gp_bn_g   = (const float*)d_in[21];
  const float* gp_bn_b   = (const float*)d_in[22];
  const float* gp_se_w1  = (const float*)d_in[23];
  const float* gp_se_w2  = (const float*)d_in[24];
  const float* fuse_w    = (const float*)d_in[25];
  const float* fuse_b    = (const float*)d_in[26];
  const float* fuse_bn_g = (const float*)d_in[27];
  const float* fuse_bn_b = (const float*)d_in[28];
  float* out = (float*)d_out;

  char* wsp = (char*)d_ws;
  auto alloc = [&](size_t bytes) -> char* {
    char* p = wsp;
    wsp += (bytes + 255) & ~(size_t)255;
    return p;
  };
  __hip_bfloat16* F0 = (__hip_bfloat16*)alloc((size_t)2 * 64 * 76 * 448 * 2);
  __hip_bfloat16* F1 = (__hip_bfloat16*)alloc((size_t)2 * 64 * 88 * 640 * 2);
  __hip_bfloat16* F2 = (__hip_bfloat16*)alloc((size_t)2 * 64 * 100 * 832 * 2);
  __hip_bfloat16* W0 = (__hip_bfloat16*)alloc((size_t)9 * 64 * 448 * 2);
  __hip_bfloat16* W1 = (__hip_bfloat16*)alloc((size_t)9 * 64 * 640 * 2);
  __hip_bfloat16* W2 = (__hip_bfloat16*)alloc((size_t)9 * 64 * 832 * 2);
  float* C0r   = (float*)alloc((size_t)3 * 3 * 64 * 4);
  float* ypart = (float*)alloc((size_t)3 * SLAB * 4);
  float* y     = ypart;          // reduced in-place into slab 0
  float* tmp   = ypart + SLAB;   // slab 1 dead after rb_k -> reuse
  float* se_meanbuf = (float*)alloc(384 * 4);   // (unused spare)
  float* A1  = (float*)alloc(384 * 4);
  float* A0  = (float*)alloc(384 * 4);
  float* xm  = (float*)alloc(128 * 4);
  float* fgp = (float*)alloc(128 * 4);
  float* fwT = (float*)alloc((size_t)12288 * 4);
  float* accz = (float*)alloc(896 * 4);  // fstat[128] | bnacc_s[192] | bnacc_q[192] | se_acc[384]
  float* fstat   = accz;
  float* bnacc_s = accz + 128;
  float* bnacc_q = accz + 320;
  float* se_acc  = accz + 512;
  (void)se_meanbuf;

  prep_k<<<4506, 256, 0, stream>>>(base_w[0], spline_w[0], base_w[1], spline_w[1],
                                   base_w[2], spline_w[2], W0, W1, W2, C0r,
                                   fuse_w, fwT, x, xm, accz);
  features_all_k<<<8448, 256, 0, stream>>>(x, F0, F1, F2);
  conv_all_k<<<576, 128, 0, stream>>>(
      (const short*)F0, (const short*)F1, (const short*)F2,
      (const short*)W0, (const short*)W1, (const short*)W2, C0r, ypart);
  rb_k<<<1536, 256, 0, stream>>>(ypart, bnacc_s, bnacc_q);
  sesum_k<<<384, 256, 0, stream>>>(y, bnacc_s, bnacc_q, bn_g[0], bn_b[0], bn_g[1], bn_b[1],
                                   bn_g[2], bn_b[2], se_acc);
  semlp_gp_k<<<7, 128, 0, stream>>>(se_acc, bnacc_s, bnacc_q, bn_g[0], bn_b[0], bn_g[1], bn_b[1],
                                    bn_g[2], bn_b[2], se_w1[0], se_w1[1], se_w1[2],
                                    se_w2[0], se_w2[1], se_w2[2], A1, A0,
                                    xm, gp_conv_w, gp_conv_b, gp_bn_g, gp_bn_b,
                                    gp_se_w1, gp_se_w2, fuse_w, fgp);
  fuse_k<<<256, 256, 0, stream>>>(y, A1, A0, fwT, fuse_b, fgp, tmp, fstat);
  final_k<<<2048, 256, 0, stream>>>(tmp, fstat, fuse_bn_g, fuse_bn_b, out);
}